// Round 1
// baseline (812.166 us; speedup 1.0000x reference)
//
#include <hip/hip_runtime.h>

typedef unsigned short u16;
typedef __attribute__((ext_vector_type(8))) __bf16 bf16x8;
typedef __attribute__((ext_vector_type(4))) float f32x4;
typedef __attribute__((ext_vector_type(8))) u16 u16x8;

#define NROWS 8192
#define K1TOT 4352

__device__ __forceinline__ u16 f2b(float f) {
  union { float f; unsigned u; } v; v.f = f;
  return (u16)((v.u + 0x7fffu + ((v.u >> 16) & 1u)) >> 16);
}
__device__ __forceinline__ float b2f(u16 h) {
  union { unsigned u; float f; } v; v.u = ((unsigned)h) << 16;
  return v.f;
}
__device__ __forceinline__ f32x4 mfma16(bf16x8 a, bf16x8 b, f32x4 c) {
  return __builtin_amdgcn_mfma_f32_16x16x32_bf16(a, b, c, 0, 0, 0);
}

// ---------------- weight transpose+cast: src f32 [R,C] -> dst bf16 [C][R] ----------------
__global__ __launch_bounds__(256) void transpose_cast(
    const float* __restrict__ src, u16* __restrict__ dst,
    int R, int C, int dstStride, long srcBatch, long dstBatch)
{
  __shared__ float tile[32][33];
  src += (long)blockIdx.z * srcBatch;
  dst += (long)blockIdx.z * dstBatch;
  const int c0 = blockIdx.x * 32, r0 = blockIdx.y * 32;
  const int tx = threadIdx.x & 31, ty = threadIdx.x >> 5;
  for (int i = ty; i < 32; i += 8) {
    int r = r0 + i, cc = c0 + tx;
    if (r < R && cc < C) tile[i][tx] = src[(long)r * C + cc];
  }
  __syncthreads();
  for (int i = ty; i < 32; i += 8) {
    int cc = c0 + i, r = r0 + tx;
    if (cc < C && r < R) dst[(long)cc * dstStride + r] = f2b(tile[tx][i]);
  }
}

// ---------------- gemm1: [x|ctx] @ [WaT|WcT ; WskipT|0]^T -> a (elu, bf16), skip (f32) ----
__global__ __launch_bounds__(256) void gemm1(
    const float* __restrict__ x, const float* __restrict__ ctx,
    const u16* __restrict__ bt1, const float* __restrict__ ba,
    const float* __restrict__ bskip, u16* __restrict__ a_bf, float* __restrict__ skip_f)
{
  __shared__ u16 As[32 * 64];
  __shared__ u16 Bs[272 * 64];
  const int tid = threadIdx.x;
  const int n0 = blockIdx.x * 32;
  const int w = tid >> 6, lane = tid & 63;
  const int q = lane >> 4, c = lane & 15;
  const int rt = w & 1, cg = w >> 1;
  const int t0 = cg ? 9 : 0;
  const int nt = cg ? 8 : 9;

  f32x4 acc[9];
#pragma unroll
  for (int i = 0; i < 9; ++i) acc[i] = f32x4{0.f, 0.f, 0.f, 0.f};

  const int sr = tid >> 3, sc = (tid & 7) * 8;

  for (int kb = 0; kb < K1TOT; kb += 64) {
    {
      const float* src = (kb < 4096)
          ? (x + (long)(n0 + sr) * 4096 + kb + sc)
          : (ctx + (long)(n0 + sr) * 256 + (kb - 4096) + sc);
      float4 v0 = ((const float4*)src)[0];
      float4 v1 = ((const float4*)src)[1];
      u16x8 o;
      o[0] = f2b(v0.x); o[1] = f2b(v0.y); o[2] = f2b(v0.z); o[3] = f2b(v0.w);
      o[4] = f2b(v1.x); o[5] = f2b(v1.y); o[6] = f2b(v1.z); o[7] = f2b(v1.w);
      *(u16x8*)&As[sr * 64 + sc] = o;
    }
    for (int rr = tid; rr < 272; rr += 256) {
      const uint4* s = (const uint4*)&bt1[(long)rr * K1TOT + kb];
      uint4* d = (uint4*)&Bs[rr * 64];
#pragma unroll
      for (int j = 0; j < 8; ++j) d[j] = s[j];
    }
    __syncthreads();
#pragma unroll
    for (int kk = 0; kk < 2; ++kk) {
      bf16x8 af = *(const bf16x8*)&As[(rt * 16 + c) * 64 + kk * 32 + q * 8];
#pragma unroll
      for (int ti = 0; ti < 9; ++ti) {
        if (ti < nt) {
          bf16x8 bfr = *(const bf16x8*)&Bs[((t0 + ti) * 16 + c) * 64 + kk * 32 + q * 8];
          acc[ti] = mfma16(af, bfr, acc[ti]);
        }
      }
    }
    __syncthreads();
  }
#pragma unroll
  for (int ti = 0; ti < 9; ++ti) {
    if (ti < nt) {
      const int col = (t0 + ti) * 16 + c;
#pragma unroll
      for (int j = 0; j < 4; ++j) {
        const long n = n0 + rt * 16 + q * 4 + j;
        float vv = acc[ti][j];
        if (col < 256) {
          vv += ba[col];
          vv = vv > 0.f ? vv : expm1f(vv);
          a_bf[n * 256 + col] = f2b(vv);
        } else {
          skip_f[n * 16 + (col - 256)] = vv + bskip[col - 256];
        }
      }
    }
  }
}

// ---------------- gemm_i: i = a @ Wi + bi -> bf16 ----------------
__global__ __launch_bounds__(256) void gemm_i(
    const u16* __restrict__ a_bf, const u16* __restrict__ wiT,
    const float* __restrict__ bi, u16* __restrict__ i_bf)
{
  __shared__ u16 As[32 * 64];
  __shared__ u16 Bs[256 * 64];
  const int tid = threadIdx.x;
  const int n0 = blockIdx.x * 32;
  const int w = tid >> 6, lane = tid & 63;
  const int q = lane >> 4, c = lane & 15;
  const int rt = w & 1, cg = w >> 1;

  f32x4 acc[8];
#pragma unroll
  for (int i = 0; i < 8; ++i) acc[i] = f32x4{0.f, 0.f, 0.f, 0.f};

  const int sr = tid >> 3, sc = (tid & 7) * 8;
  for (int kb = 0; kb < 256; kb += 64) {
    *(u16x8*)&As[sr * 64 + sc] = *(const u16x8*)&a_bf[(long)(n0 + sr) * 256 + kb + sc];
    {
      const uint4* s = (const uint4*)&wiT[(long)tid * 256 + kb];
      uint4* d = (uint4*)&Bs[tid * 64];
#pragma unroll
      for (int j = 0; j < 8; ++j) d[j] = s[j];
    }
    __syncthreads();
#pragma unroll
    for (int kk = 0; kk < 2; ++kk) {
      bf16x8 af = *(const bf16x8*)&As[(rt * 16 + c) * 64 + kk * 32 + q * 8];
#pragma unroll
      for (int ti = 0; ti < 8; ++ti) {
        bf16x8 bfr = *(const bf16x8*)&Bs[((cg * 8 + ti) * 16 + c) * 64 + kk * 32 + q * 8];
        acc[ti] = mfma16(af, bfr, acc[ti]);
      }
    }
    __syncthreads();
  }
#pragma unroll
  for (int ti = 0; ti < 8; ++ti) {
    const int col = (cg * 8 + ti) * 16 + c;
    const float bb = bi[col];
#pragma unroll
    for (int j = 0; j < 4; ++j) {
      const long n = n0 + rt * 16 + q * 4 + j;
      i_bf[n * 256 + col] = f2b(acc[ti][j] + bb);
    }
  }
}

// ---------------- joint tail: g = i@Wglu; GLU; +skip; LN(16); softmax -> sw ----------------
__global__ __launch_bounds__(256) void joint_tail(
    const u16* __restrict__ i_bf, const u16* __restrict__ wgluT,
    const float* __restrict__ bglu, const float* __restrict__ skip_f,
    const float* __restrict__ lng, const float* __restrict__ lnb,
    float* __restrict__ swout)
{
  __shared__ float wlds[32 * 257];
  __shared__ float ilds[4][256];
  const int tid = threadIdx.x;
  for (int jj = 0; jj < 32; ++jj) wlds[jj * 257 + tid] = b2f(wgluT[jj * 256 + tid]);
  const int w = tid >> 6, lane = tid & 63;
  const long n = (long)blockIdx.x * 4 + w;
  {
    const u16* src = i_bf + n * 256 + lane * 4;
    float4 f;
    f.x = b2f(src[0]); f.y = b2f(src[1]); f.z = b2f(src[2]); f.w = b2f(src[3]);
    *(float4*)&ilds[w][lane * 4] = f;
  }
  __syncthreads();
  const int cc32 = lane & 31;
  const int k0 = (lane >> 5) * 128;
  float acc = 0.f;
  for (int k = 0; k < 128; ++k) acc += ilds[w][k0 + k] * wlds[cc32 * 257 + k0 + k];
  acc += __shfl_xor(acc, 32, 64);
  const float gfull = acc + bglu[cc32];
  const int cc = lane & 15;
  const float g1 = __shfl(gfull, cc, 64);
  const float g2 = __shfl(gfull, cc + 16, 64);
  const float glu = g1 / (1.f + __expf(-g2));
  const float y = glu + skip_f[n * 16 + cc];
  float s = y, ss = y * y;
#pragma unroll
  for (int d = 1; d < 16; d <<= 1) { s += __shfl_xor(s, d, 64); ss += __shfl_xor(ss, d, 64); }
  const float m = s * (1.f / 16.f);
  const float var = ss * (1.f / 16.f) - m * m;
  const float t = (y - m) * rsqrtf(var + 1e-5f) * lng[cc] + lnb[cc];
  float mx = t;
#pragma unroll
  for (int d = 1; d < 16; d <<= 1) mx = fmaxf(mx, __shfl_xor(mx, d, 64));
  const float e = __expf(t - mx);
  float es = e;
#pragma unroll
  for (int d = 1; d < 16; d <<= 1) es += __shfl_xor(es, d, 64);
  if (lane < 16) swout[n * 16 + lane] = e / es;
}

// ---------------- per-variable fused chain ----------------
__global__ __launch_bounds__(256) void var_chain(
    const float* __restrict__ x,
    const u16* __restrict__ vWaT, const u16* __restrict__ vWiT, const u16* __restrict__ vWgluT,
    const float* __restrict__ vba, const float* __restrict__ vbi, const float* __restrict__ vbglu,
    const float* __restrict__ vlng, const float* __restrict__ vlnb,
    const float* __restrict__ sw, float* __restrict__ out)
{
  __shared__ u16 xa[32 * 256];
  __shared__ u16 t1[32 * 256];
  __shared__ u16 wt[512 * 32];
  __shared__ float red[32][2][2];
  const int tid = threadIdx.x;
  const int n0 = blockIdx.x * 32;
  const int w = tid >> 6, lane = tid & 63;
  const int q = lane >> 4, c = lane & 15;
  const int rt = w & 1, g = w >> 1;

  float outacc[8][4];
#pragma unroll
  for (int ti = 0; ti < 8; ++ti)
#pragma unroll
    for (int j = 0; j < 4; ++j) outacc[ti][j] = 0.f;

  const int sr = tid >> 3, sc = (tid & 7) * 32;

  for (int vi = 0; vi < 8; ++vi) {
    const int v = blockIdx.y * 8 + vi;
    __syncthreads();  // protect xa/t1/wt from previous iteration readers
    {
      const float* s = x + (long)(n0 + sr) * 4096 + v * 256 + sc;
      u16* dd = &xa[sr * 256 + sc];
#pragma unroll
      for (int jj = 0; jj < 4; ++jj) {
        float4 v0 = ((const float4*)s)[2 * jj];
        float4 v1 = ((const float4*)s)[2 * jj + 1];
        u16x8 o;
        o[0] = f2b(v0.x); o[1] = f2b(v0.y); o[2] = f2b(v0.z); o[3] = f2b(v0.w);
        o[4] = f2b(v1.x); o[5] = f2b(v1.y); o[6] = f2b(v1.z); o[7] = f2b(v1.w);
        *(u16x8*)(dd + jj * 8) = o;
      }
    }
    f32x4 acc[16];
    // ---- m1: av = elu(x @ WaT + ba) ----
#pragma unroll
    for (int i = 0; i < 8; ++i) acc[i] = f32x4{0.f, 0.f, 0.f, 0.f};
    for (int kc = 0; kc < 4; ++kc) {
      {
        const uint4* s = (const uint4*)&vWaT[(long)v * 65536 + (long)tid * 256 + kc * 64];
        uint4* dd = (uint4*)&wt[tid * 64];
#pragma unroll
        for (int j = 0; j < 8; ++j) dd[j] = s[j];
      }
      __syncthreads();
#pragma unroll
      for (int kk = 0; kk < 2; ++kk) {
        bf16x8 af = *(const bf16x8*)&xa[(rt * 16 + c) * 256 + kc * 64 + kk * 32 + q * 8];
#pragma unroll
        for (int ti = 0; ti < 8; ++ti) {
          bf16x8 bfr = *(const bf16x8*)&wt[((g * 8 + ti) * 16 + c) * 64 + kk * 32 + q * 8];
          acc[ti] = mfma16(af, bfr, acc[ti]);
        }
      }
      __syncthreads();
    }
#pragma unroll
    for (int ti = 0; ti < 8; ++ti) {
      const int col = (g * 8 + ti) * 16 + c;
      const float bb = vba[v * 256 + col];
#pragma unroll
      for (int j = 0; j < 4; ++j) {
        float vv = acc[ti][j] + bb;
        vv = vv > 0.f ? vv : expm1f(vv);
        t1[(rt * 16 + q * 4 + j) * 256 + col] = f2b(vv);
      }
    }
    __syncthreads();
    // ---- m2: iv = av @ WiT + bi ----
#pragma unroll
    for (int i = 0; i < 8; ++i) acc[i] = f32x4{0.f, 0.f, 0.f, 0.f};
    for (int kc = 0; kc < 4; ++kc) {
      {
        const uint4* s = (const uint4*)&vWiT[(long)v * 65536 + (long)tid * 256 + kc * 64];
        uint4* dd = (uint4*)&wt[tid * 64];
#pragma unroll
        for (int j = 0; j < 8; ++j) dd[j] = s[j];
      }
      __syncthreads();
#pragma unroll
      for (int kk = 0; kk < 2; ++kk) {
        bf16x8 af = *(const bf16x8*)&t1[(rt * 16 + c) * 256 + kc * 64 + kk * 32 + q * 8];
#pragma unroll
        for (int ti = 0; ti < 8; ++ti) {
          bf16x8 bfr = *(const bf16x8*)&wt[((g * 8 + ti) * 16 + c) * 64 + kk * 32 + q * 8];
          acc[ti] = mfma16(af, bfr, acc[ti]);
        }
      }
      __syncthreads();
    }
#pragma unroll
    for (int ti = 0; ti < 8; ++ti) {
      const int col = (g * 8 + ti) * 16 + c;
      const float bb = vbi[v * 256 + col];
#pragma unroll
      for (int j = 0; j < 4; ++j)
        t1[(rt * 16 + q * 4 + j) * 256 + col] = f2b(acc[ti][j] + bb);
    }
    __syncthreads();
    // ---- m3: gv = iv @ WgluT ----
#pragma unroll
    for (int i = 0; i < 16; ++i) acc[i] = f32x4{0.f, 0.f, 0.f, 0.f};
    for (int kc = 0; kc < 8; ++kc) {
      for (int rr = tid; rr < 512; rr += 256) {
        const uint4* s = (const uint4*)&vWgluT[(long)v * 131072 + (long)rr * 256 + kc * 32];
        uint4* dd = (uint4*)&wt[rr * 32];
#pragma unroll
        for (int j = 0; j < 4; ++j) dd[j] = s[j];
      }
      __syncthreads();
      {
        bf16x8 af = *(const bf16x8*)&t1[(rt * 16 + c) * 256 + kc * 32 + q * 8];
#pragma unroll
        for (int ti = 0; ti < 16; ++ti) {
          const int ct = (ti < 8) ? (g * 8 + ti) : (16 + g * 8 + (ti - 8));
          bf16x8 bfr = *(const bf16x8*)&wt[(ct * 16 + c) * 32 + q * 8];
          acc[ti] = mfma16(af, bfr, acc[ti]);
        }
      }
      __syncthreads();
    }
    // ---- epilogue: GLU + residual + LN + weighted accumulate ----
    float rs[4] = {0.f, 0.f, 0.f, 0.f}, rss[4] = {0.f, 0.f, 0.f, 0.f};
#pragma unroll
    for (int ti = 0; ti < 8; ++ti) {
      const int col = (g * 8 + ti) * 16 + c;
      const float b1 = vbglu[v * 512 + col];
      const float b2 = vbglu[v * 512 + 256 + col];
#pragma unroll
      for (int j = 0; j < 4; ++j) {
        const int row = rt * 16 + q * 4 + j;
        const float g1 = acc[ti][j] + b1;
        const float g2 = acc[ti + 8][j] + b2;
        const float glu = g1 / (1.f + __expf(-g2));
        const float r = glu + b2f(xa[row * 256 + col]);
        acc[ti][j] = r;
        rs[j] += r; rss[j] += r * r;
      }
    }
#pragma unroll
    for (int j = 0; j < 4; ++j) {
#pragma unroll
      for (int dm = 1; dm < 16; dm <<= 1) {
        rs[j] += __shfl_xor(rs[j], dm, 64);
        rss[j] += __shfl_xor(rss[j], dm, 64);
      }
    }
    if (c == 0) {
#pragma unroll
      for (int j = 0; j < 4; ++j) {
        red[rt * 16 + q * 4 + j][g][0] = rs[j];
        red[rt * 16 + q * 4 + j][g][1] = rss[j];
      }
    }
    __syncthreads();
    float mu[4], inv[4], wv[4];
#pragma unroll
    for (int j = 0; j < 4; ++j) {
      const int row = rt * 16 + q * 4 + j;
      const float st = red[row][0][0] + red[row][1][0];
      const float sst = red[row][0][1] + red[row][1][1];
      const float mm = st * (1.f / 256.f);
      const float va = sst * (1.f / 256.f) - mm * mm;
      mu[j] = mm;
      inv[j] = rsqrtf(va + 1e-5f);
      wv[j] = sw[(long)(n0 + row) * 16 + v];
    }
#pragma unroll
    for (int ti = 0; ti < 8; ++ti) {
      const int col = (g * 8 + ti) * 16 + c;
      const float lg = vlng[v * 256 + col];
      const float lb = vlnb[v * 256 + col];
#pragma unroll
      for (int j = 0; j < 4; ++j) {
        const float tv = (acc[ti][j] - mu[j]) * inv[j] * lg + lb;
        outacc[ti][j] += tv * wv[j];
      }
    }
  }
#pragma unroll
  for (int ti = 0; ti < 8; ++ti) {
    const int col = (g * 8 + ti) * 16 + c;
#pragma unroll
    for (int j = 0; j < 4; ++j) {
      const long n = n0 + rt * 16 + q * 4 + j;
      atomicAdd(out + n * 256 + col, outacc[ti][j]);
    }
  }
}

extern "C" void kernel_launch(void* const* d_in, const int* in_sizes, int n_in,
                              void* d_out, int out_size, void* d_ws, size_t ws_size,
                              hipStream_t stream) {
  const float* x     = (const float*)d_in[0];
  const float* ctx   = (const float*)d_in[1];
  const float* jWa   = (const float*)d_in[2];
  const float* jba   = (const float*)d_in[3];
  const float* jWc   = (const float*)d_in[4];
  const float* jWi   = (const float*)d_in[5];
  const float* jbi   = (const float*)d_in[6];
  const float* jWglu = (const float*)d_in[7];
  const float* jbglu = (const float*)d_in[8];
  const float* jWskip= (const float*)d_in[9];
  const float* jbskip= (const float*)d_in[10];
  const float* jlng  = (const float*)d_in[11];
  const float* jlnb  = (const float*)d_in[12];
  const float* vWa   = (const float*)d_in[13];
  const float* vba   = (const float*)d_in[14];
  const float* vWi   = (const float*)d_in[15];
  const float* vbi   = (const float*)d_in[16];
  const float* vWglu = (const float*)d_in[17];
  const float* vbglu = (const float*)d_in[18];
  const float* vlng  = (const float*)d_in[19];
  const float* vlnb  = (const float*)d_in[20];
  float* out = (float*)d_out;

  char* ws = (char*)d_ws;
  size_t off = 0;
  auto alloc = [&](size_t bytes) { void* p = ws + off; off += (bytes + 255) & ~(size_t)255; return p; };
  u16* bt1     = (u16*)alloc((size_t)272 * 4352 * 2);
  u16* wiT     = (u16*)alloc((size_t)256 * 256 * 2);
  u16* wgluT   = (u16*)alloc((size_t)32 * 256 * 2);
  u16* vWaT    = (u16*)alloc((size_t)16 * 256 * 256 * 2);
  u16* vWiT    = (u16*)alloc((size_t)16 * 256 * 256 * 2);
  u16* vWgluT  = (u16*)alloc((size_t)16 * 512 * 256 * 2);
  u16* a_bf    = (u16*)alloc((size_t)8192 * 256 * 2);
  u16* i_bf    = (u16*)alloc((size_t)8192 * 256 * 2);
  float* skipf = (float*)alloc((size_t)8192 * 16 * 4);

  hipMemsetAsync(bt1, 0, (size_t)272 * 4352 * 2, stream);
  hipMemsetAsync(out, 0, (size_t)8192 * 256 * 4, stream);

  dim3 blk(256);
  transpose_cast<<<dim3(8, 128, 1),  blk, 0, stream>>>(jWa,   bt1,              4096, 256, 4352, 0, 0);
  transpose_cast<<<dim3(8, 8, 1),    blk, 0, stream>>>(jWc,   bt1 + 4096,       256,  256, 4352, 0, 0);
  transpose_cast<<<dim3(1, 128, 1),  blk, 0, stream>>>(jWskip,bt1 + 256 * 4352, 4096, 16,  4352, 0, 0);
  transpose_cast<<<dim3(8, 8, 1),    blk, 0, stream>>>(jWi,   wiT,   256, 256, 256, 0, 0);
  transpose_cast<<<dim3(1, 8, 1),    blk, 0, stream>>>(jWglu, wgluT, 256, 32,  256, 0, 0);
  transpose_cast<<<dim3(8, 8, 16),   blk, 0, stream>>>(vWa,   vWaT,   256, 256, 256, 65536, 65536);
  transpose_cast<<<dim3(8, 8, 16),   blk, 0, stream>>>(vWi,   vWiT,   256, 256, 256, 65536, 65536);
  transpose_cast<<<dim3(16, 8, 16),  blk, 0, stream>>>(vWglu, vWgluT, 256, 512, 256, 131072, 131072);

  gemm1<<<dim3(256), blk, 0, stream>>>(x, ctx, bt1, jba, jbskip, a_bf, skipf);
  gemm_i<<<dim3(256), blk, 0, stream>>>(a_bf, wiT, jbi, i_bf);
  joint_tail<<<dim3(2048), blk, 0, stream>>>(i_bf, wgluT, jbglu, skipf, jlng, jlnb,
                                             out + (size_t)8192 * 256);
  var_chain<<<dim3(256, 2), blk, 0, stream>>>(x, vWaT, vWiT, vWgluT, vba, vbi, vbglu,
                                              vlng, vlnb, out + (size_t)8192 * 256, out);
}

// Round 3
// 567.094 us; speedup vs baseline: 1.4322x; 1.4322x over previous
//
#include <hip/hip_runtime.h>

typedef unsigned short u16;
typedef __attribute__((ext_vector_type(8))) __bf16 bf16x8;
typedef __attribute__((ext_vector_type(4))) float f32x4;
typedef __attribute__((ext_vector_type(8))) u16 u16x8;

__device__ __forceinline__ u16 f2b(float f) {
  union { float f; unsigned u; } v; v.f = f;
  return (u16)((v.u + 0x7fffu + ((v.u >> 16) & 1u)) >> 16);
}
__device__ __forceinline__ float b2f(u16 h) {
  union { unsigned u; float f; } v; v.u = ((unsigned)h) << 16;
  return v.f;
}
__device__ __forceinline__ f32x4 mfma16(bf16x8 a, bf16x8 b, f32x4 c) {
  return __builtin_amdgcn_mfma_f32_16x16x32_bf16(a, b, c, 0, 0, 0);
}
__device__ __forceinline__ void gl_lds16(const void* g, void* l) {
  __builtin_amdgcn_global_load_lds(
      (const __attribute__((address_space(1))) void*)g,
      (__attribute__((address_space(3))) void*)l, 16, 0, 0);
}
__device__ __forceinline__ u16x8 cvt8(float4 a, float4 b) {
  u16x8 o;
  o[0] = f2b(a.x); o[1] = f2b(a.y); o[2] = f2b(a.z); o[3] = f2b(a.w);
  o[4] = f2b(b.x); o[5] = f2b(b.y); o[6] = f2b(b.z); o[7] = f2b(b.w);
  return o;
}

// ---------------- weight transpose+cast: src f32 [R,C] -> dst bf16 [C][R] (linear) ----------
__global__ __launch_bounds__(256) void transpose_cast(
    const float* __restrict__ src, u16* __restrict__ dst,
    int R, int C, int dstStride, long srcBatch, long dstBatch)
{
  __shared__ float tile[32][33];
  src += (long)blockIdx.z * srcBatch;
  dst += (long)blockIdx.z * dstBatch;
  const int c0 = blockIdx.x * 32, r0 = blockIdx.y * 32;
  const int tx = threadIdx.x & 31, ty = threadIdx.x >> 5;
  for (int i = ty; i < 32; i += 8) {
    int r = r0 + i, cc = c0 + tx;
    if (r < R && cc < C) tile[i][tx] = src[(long)r * C + cc];
  }
  __syncthreads();
  for (int i = ty; i < 32; i += 8) {
    int cc = c0 + i, r = r0 + tx;
    if (cc < C && r < R) dst[(long)cc * dstStride + r] = f2b(tile[tx][i]);
  }
}

// ---- var Wa/Wi -> pre-swizzled 32KB tiles: per (v,kc): [256 n][64 k2], chunk = n*8 + ((k2/8)^(n&7))
__global__ __launch_bounds__(256) void var_w_prep(
    const float* __restrict__ W, u16* __restrict__ dstbase, int rbase)
{
  const int v = blockIdx.x;   // 16
  const int kc = blockIdx.y;  // 4
  const int n = threadIdx.x;  // 256
  const float* src = W + (size_t)v * 65536 + (size_t)kc * 64 * 256 + n;
  u16* dst = dstbase + (size_t)v * 262144 + (size_t)(rbase + kc) * 16384;
#pragma unroll
  for (int l = 0; l < 8; ++l) {
    u16x8 o;
#pragma unroll
    for (int e = 0; e < 8; ++e) o[e] = f2b(src[(l * 8 + e) * 256]);
    const int chunk = n * 8 + (l ^ (n & 7));
    *(u16x8*)&dst[chunk * 8] = o;
  }
}

// ---- var Wglu -> tiles: per (v,kc): [512 n][32 k2], chunk = (n>>1)*8 + (((n&1)*4 + k2/8) ^ ((n>>1)&7))
__global__ __launch_bounds__(256) void var_wglu_prep(
    const float* __restrict__ W, u16* __restrict__ dstbase)
{
  const int v = blockIdx.x;   // 16
  const int kc = blockIdx.y;  // 8
  u16* dst = dstbase + (size_t)v * 262144 + (size_t)(8 + kc) * 16384;
#pragma unroll
  for (int half = 0; half < 2; ++half) {
    const int n = threadIdx.x + half * 256;
    const float* src = W + (size_t)v * 131072 + (size_t)kc * 32 * 512 + n;
    const int s = n >> 1;
#pragma unroll
    for (int l = 0; l < 4; ++l) {
      u16x8 o;
#pragma unroll
      for (int e = 0; e < 8; ++e) o[e] = f2b(src[(l * 8 + e) * 512]);
      const int chunk = s * 8 + ((((n & 1) * 4 + l)) ^ (s & 7));
      *(u16x8*)&dst[chunk * 8] = o;
    }
  }
}

// ---------------- gemm1: [x|ctx] @ [WaT|WcT ; WskipT|0]^T -> a (elu, bf16), skip (f32) ----
#define K1TOT 4352
__global__ __launch_bounds__(256, 3) void gemm1(
    const float* __restrict__ x, const float* __restrict__ ctx,
    const u16* __restrict__ bt1, const float* __restrict__ ba,
    const float* __restrict__ bskip, u16* __restrict__ a_bf, float* __restrict__ skip_f)
{
  __shared__ u16 As[32 * 64];
  __shared__ u16 Bs[288 * 64];
  const int tid = threadIdx.x;
  const int n0 = blockIdx.x * 32;
  const int w = tid >> 6, lane = tid & 63;
  const int q = lane >> 4, c = lane & 15;
  const int rt = w & 1, cg = w >> 1;
  const int t0 = cg ? 9 : 0;
  const int nt = cg ? 8 : 9;

  f32x4 acc[9];
#pragma unroll
  for (int i = 0; i < 9; ++i) acc[i] = f32x4{0.f, 0.f, 0.f, 0.f};

  const int sr = tid >> 3, sp = tid & 7;
  const int sl = sp ^ (sr & 7);

  for (int kb = 0; kb < K1TOT; kb += 64) {
    { // A stage: linear LDS write, column-permuted source (swizzle baked in)
      const float* s = (kb < 4096)
          ? (x + (size_t)(n0 + sr) * 4096 + kb + sl * 8)
          : (ctx + (size_t)(n0 + sr) * 256 + (kb - 4096) + sl * 8);
      float4 v0 = ((const float4*)s)[0];
      float4 v1 = ((const float4*)s)[1];
      *(u16x8*)&As[tid * 8] = cvt8(v0, v1);
    }
    // B stage: async global->LDS, linear dst, permuted per-lane src
#pragma unroll
    for (int i = 0; i < 9; ++i) {
      const int cb = (i * 4 + w) * 64;
      const int cid = cb + lane;
      const int row = cid >> 3, p = cid & 7;
      const int l = p ^ (row & 7);
      const u16* src = (row < 272) ? (bt1 + (size_t)row * K1TOT + kb + l * 8) : bt1;
      gl_lds16(src, &Bs[cb * 8]);
    }
    __syncthreads();
#pragma unroll
    for (int kk = 0; kk < 2; ++kk) {
      const int arow = rt * 16 + c;
      bf16x8 af = *(const bf16x8*)&As[(arow * 64 + kk * 32 + q * 8) ^ ((arow & 7) << 3)];
#pragma unroll
      for (int ti = 0; ti < 9; ++ti) {
        if (ti < nt) {
          const int n16 = (t0 + ti) * 16 + c;
          bf16x8 bfr = *(const bf16x8*)&Bs[(n16 * 64 + kk * 32 + q * 8) ^ ((n16 & 7) << 3)];
          acc[ti] = mfma16(af, bfr, acc[ti]);
        }
      }
    }
    __syncthreads();
  }
#pragma unroll
  for (int ti = 0; ti < 9; ++ti) {
    if (ti < nt) {
      const int col = (t0 + ti) * 16 + c;
#pragma unroll
      for (int j = 0; j < 4; ++j) {
        const long n = n0 + rt * 16 + q * 4 + j;
        float vv = acc[ti][j];
        if (col < 256) {
          vv += ba[col];
          vv = vv > 0.f ? vv : expm1f(vv);
          a_bf[n * 256 + col] = f2b(vv);
        } else {
          skip_f[n * 16 + (col - 256)] = vv + bskip[col - 256];
        }
      }
    }
  }
}

// ---------------- gemm_i: i = a @ Wi + bi -> bf16 ----------------
__global__ __launch_bounds__(256, 3) void gemm_i(
    const u16* __restrict__ a_bf, const u16* __restrict__ wiT,
    const float* __restrict__ bi, u16* __restrict__ i_bf)
{
  __shared__ u16 As[32 * 64];
  __shared__ u16 Bs[256 * 64];
  const int tid = threadIdx.x;
  const int n0 = blockIdx.x * 32;
  const int w = tid >> 6, lane = tid & 63;
  const int q = lane >> 4, c = lane & 15;
  const int rt = w & 1, cg = w >> 1;

  f32x4 acc[8];
#pragma unroll
  for (int i = 0; i < 8; ++i) acc[i] = f32x4{0.f, 0.f, 0.f, 0.f};

  for (int kb = 0; kb < 256; kb += 64) {
    { // A via global_load_lds (a_bf linear, permuted src)
      const int row = tid >> 3, p = tid & 7;
      const int l = p ^ (row & 7);
      gl_lds16(a_bf + (size_t)(n0 + row) * 256 + kb + l * 8, &As[w * 512]);
    }
#pragma unroll
    for (int i = 0; i < 8; ++i) {
      const int cb = (i * 4 + w) * 64;
      const int cid = cb + lane;
      const int row = cid >> 3, p = cid & 7;
      const int l = p ^ (row & 7);
      gl_lds16(wiT + (size_t)row * 256 + kb + l * 8, &Bs[cb * 8]);
    }
    __syncthreads();
#pragma unroll
    for (int kk = 0; kk < 2; ++kk) {
      const int arow = rt * 16 + c;
      bf16x8 af = *(const bf16x8*)&As[(arow * 64 + kk * 32 + q * 8) ^ ((arow & 7) << 3)];
#pragma unroll
      for (int ti = 0; ti < 8; ++ti) {
        const int n16 = (cg * 8 + ti) * 16 + c;
        bf16x8 bfr = *(const bf16x8*)&Bs[(n16 * 64 + kk * 32 + q * 8) ^ ((n16 & 7) << 3)];
        acc[ti] = mfma16(af, bfr, acc[ti]);
      }
    }
    __syncthreads();
  }
#pragma unroll
  for (int ti = 0; ti < 8; ++ti) {
    const int col = (cg * 8 + ti) * 16 + c;
    const float bb = bi[col];
#pragma unroll
    for (int j = 0; j < 4; ++j) {
      const long n = n0 + rt * 16 + q * 4 + j;
      i_bf[n * 256 + col] = f2b(acc[ti][j] + bb);
    }
  }
}

// ---------------- joint tail: g = i@Wglu; GLU; +skip; LN(16); softmax -> sw ----------------
__global__ __launch_bounds__(256) void joint_tail(
    const u16* __restrict__ i_bf, const u16* __restrict__ wgluT,
    const float* __restrict__ bglu, const float* __restrict__ skip_f,
    const float* __restrict__ lng, const float* __restrict__ lnb,
    float* __restrict__ swout)
{
  __shared__ float wlds[32 * 257];
  __shared__ float ilds[4][256];
  const int tid = threadIdx.x;
  for (int jj = 0; jj < 32; ++jj) wlds[jj * 257 + tid] = b2f(wgluT[jj * 256 + tid]);
  const int w = tid >> 6, lane = tid & 63;
  const long n = (long)blockIdx.x * 4 + w;
  {
    const u16* src = i_bf + n * 256 + lane * 4;
    float4 f;
    f.x = b2f(src[0]); f.y = b2f(src[1]); f.z = b2f(src[2]); f.w = b2f(src[3]);
    *(float4*)&ilds[w][lane * 4] = f;
  }
  __syncthreads();
  const int cc32 = lane & 31;
  const int k0 = (lane >> 5) * 128;
  float acc = 0.f;
  for (int k = 0; k < 128; ++k) acc += ilds[w][k0 + k] * wlds[cc32 * 257 + k0 + k];
  acc += __shfl_xor(acc, 32, 64);
  const float gfull = acc + bglu[cc32];
  const int cc = lane & 15;
  const float g1 = __shfl(gfull, cc, 64);
  const float g2 = __shfl(gfull, cc + 16, 64);
  const float glu = g1 / (1.f + __expf(-g2));
  const float y = glu + skip_f[n * 16 + cc];
  float s = y, ss = y * y;
#pragma unroll
  for (int d = 1; d < 16; d <<= 1) { s += __shfl_xor(s, d, 64); ss += __shfl_xor(ss, d, 64); }
  const float m = s * (1.f / 16.f);
  const float var = ss * (1.f / 16.f) - m * m;
  const float t = (y - m) * rsqrtf(var + 1e-5f) * lng[cc] + lnb[cc];
  float mx = t;
#pragma unroll
  for (int d = 1; d < 16; d <<= 1) mx = fmaxf(mx, __shfl_xor(mx, d, 64));
  const float e = __expf(t - mx);
  float es = e;
#pragma unroll
  for (int d = 1; d < 16; d <<= 1) es += __shfl_xor(es, d, 64);
  if (lane < 16) swout[n * 16 + lane] = e / es;
}

// ---------------- per-variable fused chain (M=64, 8 waves, swizzled LDS) ----------------
// Single-buffer textbook staging: stage tile -> barrier -> MFMA -> barrier (m97 pattern).
__global__ __launch_bounds__(512, 1) void var_chain(
    const float* __restrict__ x, const u16* __restrict__ varw,
    const float* __restrict__ vba, const float* __restrict__ vbi,
    const float* __restrict__ vbglu, const float* __restrict__ vlng,
    const float* __restrict__ vlnb, const float* __restrict__ sw,
    float* __restrict__ out)
{
  extern __shared__ u16 smem[];
  u16* const xa = smem;                        // 16384 u16 (32KB)
  u16* const t1 = smem + 16384;                // 32KB
  u16* const wt = smem + 32768;                // 32KB (single buffer)
  float* const red   = (float*)(smem + 49152); // 64*16 floats (byte 98304)
  float* const muinv = red + 1024;             // 64*2 floats

  const int tid = threadIdx.x;
  const int w = tid >> 6, lane = tid & 63;
  const int q = lane >> 4, c = lane & 15;
  const int rt0 = (w & 1) << 1, cg = w >> 1;
  const int n0 = blockIdx.x * 64;
  const int vbase = blockIdx.y * 8;

  f32x4 outacc[4][2];
#pragma unroll
  for (int p = 0; p < 4; ++p)
#pragma unroll
    for (int u = 0; u < 2; ++u) outacc[p][u] = f32x4{0.f, 0.f, 0.f, 0.f};

  float4 xpre[8];
#pragma unroll
  for (int jj = 0; jj < 4; ++jj) {
    const int cid = jj * 512 + tid;
    const int r = cid >> 5, p = cid & 31;
    const int l = (p & 24) | ((p & 7) ^ (r & 7));
    const float* s = x + (size_t)(n0 + r) * 4096 + (size_t)vbase * 256 + l * 8;
    xpre[jj * 2]     = ((const float4*)s)[0];
    xpre[jj * 2 + 1] = ((const float4*)s)[1];
  }

  for (int vi = 0; vi < 8; ++vi) {
    const int v = vbase + vi;
    const u16* vtiles = varw + (size_t)v * 262144;

    // ---- write xa (linear chunks; source columns pre-permuted) ----
#pragma unroll
    for (int jj = 0; jj < 4; ++jj) {
      const int cid = jj * 512 + tid;
      *(u16x8*)&xa[cid * 8] = cvt8(xpre[jj * 2], xpre[jj * 2 + 1]);
    }
    __syncthreads();  // xa visible; also separates prev epilogue reads

    f32x4 acc2[2][4];
#pragma unroll
    for (int p = 0; p < 2; ++p)
#pragma unroll
      for (int ti = 0; ti < 4; ++ti) acc2[p][ti] = f32x4{0.f, 0.f, 0.f, 0.f};

    // ---- m1: av = elu(x @ WaT + ba) ----
    for (int kc = 0; kc < 4; ++kc) {
      { // stage tile kc (Wa) into wt
        const u16* tb = vtiles + (size_t)kc * 16384;
#pragma unroll
        for (int i = 0; i < 4; ++i) {
          const int cb = (i * 8 + w) * 64;
          gl_lds16(tb + (size_t)(cb + lane) * 8, wt + (size_t)cb * 8);
        }
      }
      __syncthreads();  // stage complete
#pragma unroll
      for (int kk = 0; kk < 2; ++kk) {
        const int r0 = rt0 * 16 + c, r1 = (rt0 + 1) * 16 + c;
        bf16x8 a0 = *(const bf16x8*)&xa[(r0 * 256 + kc * 64 + kk * 32 + q * 8) ^ ((r0 & 7) << 3)];
        bf16x8 a1 = *(const bf16x8*)&xa[(r1 * 256 + kc * 64 + kk * 32 + q * 8) ^ ((r1 & 7) << 3)];
#pragma unroll
        for (int ti = 0; ti < 4; ++ti) {
          const int n16 = (cg * 4 + ti) * 16 + c;
          bf16x8 b = *(const bf16x8*)&wt[(n16 * 64 + kk * 32 + q * 8) ^ ((n16 & 7) << 3)];
          acc2[0][ti] = mfma16(a0, b, acc2[0][ti]);
          acc2[1][ti] = mfma16(a1, b, acc2[1][ti]);
        }
      }
      __syncthreads();  // reads complete before next stage overwrites wt
    }
    // write av -> t1 (no reader of t1 in m1; last barrier already passed)
#pragma unroll
    for (int p = 0; p < 2; ++p)
#pragma unroll
      for (int ti = 0; ti < 4; ++ti) {
        const int col = (cg * 4 + ti) * 16 + c;
        const float bb = vba[v * 256 + col];
#pragma unroll
        for (int j = 0; j < 4; ++j) {
          const int row = (rt0 + p) * 16 + q * 4 + j;
          float vv = acc2[p][ti][j] + bb;
          vv = vv > 0.f ? vv : expm1f(vv);
          t1[(row * 256 + col) ^ ((row & 7) << 3)] = f2b(vv);
        }
      }
    __syncthreads();  // t1(av) visible

    // ---- m2: iv = av @ WiT + bi ----
#pragma unroll
    for (int p = 0; p < 2; ++p)
#pragma unroll
      for (int ti = 0; ti < 4; ++ti) acc2[p][ti] = f32x4{0.f, 0.f, 0.f, 0.f};
    for (int kc = 0; kc < 4; ++kc) {
      {
        const u16* tb = vtiles + (size_t)(4 + kc) * 16384;
#pragma unroll
        for (int i = 0; i < 4; ++i) {
          const int cb = (i * 8 + w) * 64;
          gl_lds16(tb + (size_t)(cb + lane) * 8, wt + (size_t)cb * 8);
        }
      }
      __syncthreads();
#pragma unroll
      for (int kk = 0; kk < 2; ++kk) {
        const int r0 = rt0 * 16 + c, r1 = (rt0 + 1) * 16 + c;
        bf16x8 a0 = *(const bf16x8*)&t1[(r0 * 256 + kc * 64 + kk * 32 + q * 8) ^ ((r0 & 7) << 3)];
        bf16x8 a1 = *(const bf16x8*)&t1[(r1 * 256 + kc * 64 + kk * 32 + q * 8) ^ ((r1 & 7) << 3)];
#pragma unroll
        for (int ti = 0; ti < 4; ++ti) {
          const int n16 = (cg * 4 + ti) * 16 + c;
          bf16x8 b = *(const bf16x8*)&wt[(n16 * 64 + kk * 32 + q * 8) ^ ((n16 & 7) << 3)];
          acc2[0][ti] = mfma16(a0, b, acc2[0][ti]);
          acc2[1][ti] = mfma16(a1, b, acc2[1][ti]);
        }
      }
      __syncthreads();
    }
    // all m2 reads of t1(av) done (barrier above) -> overwrite with iv
#pragma unroll
    for (int p = 0; p < 2; ++p)
#pragma unroll
      for (int ti = 0; ti < 4; ++ti) {
        const int col = (cg * 4 + ti) * 16 + c;
        const float bb = vbi[v * 256 + col];
#pragma unroll
        for (int j = 0; j < 4; ++j) {
          const int row = (rt0 + p) * 16 + q * 4 + j;
          t1[(row * 256 + col) ^ ((row & 7) << 3)] = f2b(acc2[p][ti][j] + bb);
        }
      }
    __syncthreads();  // t1(iv) visible

    // ---- m3: gv = iv @ WgluT (N=512) ----
    f32x4 acc3[4][4];
#pragma unroll
    for (int p = 0; p < 4; ++p)
#pragma unroll
      for (int u = 0; u < 4; ++u) acc3[p][u] = f32x4{0.f, 0.f, 0.f, 0.f};
    for (int kc = 0; kc < 8; ++kc) {
      {
        const u16* tb = vtiles + (size_t)(8 + kc) * 16384;
#pragma unroll
        for (int i = 0; i < 4; ++i) {
          const int cb = (i * 8 + w) * 64;
          gl_lds16(tb + (size_t)(cb + lane) * 8, wt + (size_t)cb * 8);
        }
      }
      if (vi < 7 && kc == 5) {  // register-prefetch x for next variable (regs only, race-free)
#pragma unroll
        for (int jj = 0; jj < 4; ++jj) {
          const int cid = jj * 512 + tid;
          const int r = cid >> 5, p = cid & 31;
          const int l = (p & 24) | ((p & 7) ^ (r & 7));
          const float* s = x + (size_t)(n0 + r) * 4096 + (size_t)(v + 1) * 256 + l * 8;
          xpre[jj * 2]     = ((const float4*)s)[0];
          xpre[jj * 2 + 1] = ((const float4*)s)[1];
        }
      }
      __syncthreads();  // stage complete
      bf16x8 a[4];
#pragma unroll
      for (int p = 0; p < 4; ++p) {
        const int r = p * 16 + c;
        a[p] = *(const bf16x8*)&t1[(r * 256 + kc * 32 + q * 8) ^ ((r & 7) << 3)];
      }
#pragma unroll
      for (int u = 0; u < 4; ++u) {
        const int gt = 2 * w + (u & 1) + (u >> 1) * 16;
        const int n = gt * 16 + c;
        const int idx = (n >> 1) * 64 + ((((n & 1) * 4 + q) ^ ((n >> 1) & 7)) * 8);
        bf16x8 b = *(const bf16x8*)&wt[idx];
#pragma unroll
        for (int p = 0; p < 4; ++p) acc3[p][u] = mfma16(a[p], b, acc3[p][u]);
      }
      __syncthreads();  // reads complete before next stage
    }

    // ---- epilogue: GLU + residual + LN + weighted accumulate ----
    float b1v[2], b2v[2], lgv[2], lbv[2];
#pragma unroll
    for (int u01 = 0; u01 < 2; ++u01) {
      const int col = w * 32 + u01 * 16 + c;
      b1v[u01] = vbglu[v * 512 + col];
      b2v[u01] = vbglu[v * 512 + 256 + col];
      lgv[u01] = vlng[v * 256 + col];
      lbv[u01] = vlnb[v * 256 + col];
    }
    float rs[4][4], rss[4][4];
#pragma unroll
    for (int p = 0; p < 4; ++p)
#pragma unroll
      for (int j = 0; j < 4; ++j) { rs[p][j] = 0.f; rss[p][j] = 0.f; }
#pragma unroll
    for (int p = 0; p < 4; ++p)
#pragma unroll
      for (int u01 = 0; u01 < 2; ++u01) {
        const int col = w * 32 + u01 * 16 + c;
#pragma unroll
        for (int j = 0; j < 4; ++j) {
          const int row = p * 16 + q * 4 + j;
          const float g1 = acc3[p][u01][j] + b1v[u01];
          const float g2 = acc3[p][u01 + 2][j] + b2v[u01];
          const float glu = g1 / (1.f + __expf(-g2));
          const float r = glu + b2f(xa[(row * 256 + col) ^ ((row & 7) << 3)]);
          acc3[p][u01][j] = r;
          rs[p][j] += r; rss[p][j] += r * r;
        }
      }
#pragma unroll
    for (int p = 0; p < 4; ++p)
#pragma unroll
      for (int j = 0; j < 4; ++j)
#pragma unroll
        for (int d = 1; d < 16; d <<= 1) {
          rs[p][j]  += __shfl_xor(rs[p][j], d, 64);
          rss[p][j] += __shfl_xor(rss[p][j], d, 64);
        }
    if (c == 0) {
#pragma unroll
      for (int p = 0; p < 4; ++p)
#pragma unroll
        for (int j = 0; j < 4; ++j) {
          const int row = p * 16 + q * 4 + j;
          red[row * 16 + w * 2]     = rs[p][j];
          red[row * 16 + w * 2 + 1] = rss[p][j];
        }
    }
    __syncthreads();
    if (tid < 64) {
      float ms = 0.f, vs = 0.f;
#pragma unroll
      for (int ww = 0; ww < 8; ++ww) { ms += red[tid * 16 + ww * 2]; vs += red[tid * 16 + ww * 2 + 1]; }
      const float mm = ms * (1.f / 256.f);
      muinv[tid * 2]     = mm;
      muinv[tid * 2 + 1] = rsqrtf(vs * (1.f / 256.f) - mm * mm + 1e-5f);
    }
    __syncthreads();
#pragma unroll
    for (int p = 0; p < 4; ++p) {
#pragma unroll
      for (int j = 0; j < 4; ++j) {
        const int row = p * 16 + q * 4 + j;
        const float mu = muinv[row * 2], inv = muinv[row * 2 + 1];
        const float wv = sw[(size_t)(n0 + row) * 16 + v];
#pragma unroll
        for (int u01 = 0; u01 < 2; ++u01) {
          const float tv = (acc3[p][u01][j] - mu) * inv * lgv[u01] + lbv[u01];
          outacc[p][u01][j] += tv * wv;
        }
      }
    }
  }

#pragma unroll
  for (int p = 0; p < 4; ++p)
#pragma unroll
    for (int u01 = 0; u01 < 2; ++u01) {
      const int col = w * 32 + u01 * 16 + c;
#pragma unroll
      for (int j = 0; j < 4; ++j) {
        const int row = p * 16 + q * 4 + j;
        atomicAdd(&out[(size_t)(n0 + row) * 256 + col], outacc[p][u01][j]);
      }
    }
}

extern "C" void kernel_launch(void* const* d_in, const int* in_sizes, int n_in,
                              void* d_out, int out_size, void* d_ws, size_t ws_size,
                              hipStream_t stream) {
  const float* x     = (const float*)d_in[0];
  const float* ctx   = (const float*)d_in[1];
  const float* jWa   = (const float*)d_in[2];
  const float* jba   = (const float*)d_in[3];
  const float* jWc   = (const float*)d_in[4];
  const float* jWi   = (const float*)d_in[5];
  const float* jbi   = (const float*)d_in[6];
  const float* jWglu = (const float*)d_in[7];
  const float* jbglu = (const float*)d_in[8];
  const float* jWskip= (const float*)d_in[9];
  const float* jbskip= (const float*)d_in[10];
  const float* jlng  = (const float*)d_in[11];
  const float* jlnb  = (const float*)d_in[12];
  const float* vWa   = (const float*)d_in[13];
  const float* vba   = (const float*)d_in[14];
  const float* vWi   = (const float*)d_in[15];
  const float* vbi   = (const float*)d_in[16];
  const float* vWglu = (const float*)d_in[17];
  const float* vbglu = (const float*)d_in[18];
  const float* vlng  = (const float*)d_in[19];
  const float* vlnb  = (const float*)d_in[20];
  float* out = (float*)d_out;

  char* ws = (char*)d_ws;
  size_t off = 0;
  auto alloc = [&](size_t bytes) { void* p = ws + off; off += (bytes + 255) & ~(size_t)255; return p; };
  u16* bt1     = (u16*)alloc((size_t)272 * 4352 * 2);
  u16* wiT     = (u16*)alloc((size_t)256 * 256 * 2);
  u16* wgluT   = (u16*)alloc((size_t)32 * 256 * 2);
  u16* varw    = (u16*)alloc((size_t)16 * 262144 * 2);   // 16 vars x 16 tiles x 32KB
  u16* a_bf    = (u16*)alloc((size_t)8192 * 256 * 2);
  u16* i_bf    = (u16*)alloc((size_t)8192 * 256 * 2);
  float* skipf = (float*)alloc((size_t)8192 * 16 * 4);

  hipMemsetAsync(bt1, 0, (size_t)272 * 4352 * 2, stream);
  hipMemsetAsync(out, 0, (size_t)8192 * 256 * 4, stream);

  dim3 blk(256);
  transpose_cast<<<dim3(8, 128, 1),  blk, 0, stream>>>(jWa,   bt1,              4096, 256, 4352, 0, 0);
  transpose_cast<<<dim3(8, 8, 1),    blk, 0, stream>>>(jWc,   bt1 + 4096,       256,  256, 4352, 0, 0);
  transpose_cast<<<dim3(1, 128, 1),  blk, 0, stream>>>(jWskip,bt1 + 256 * 4352, 4096, 16,  4352, 0, 0);
  transpose_cast<<<dim3(8, 8, 1),    blk, 0, stream>>>(jWi,   wiT,   256, 256, 256, 0, 0);
  transpose_cast<<<dim3(1, 8, 1),    blk, 0, stream>>>(jWglu, wgluT, 256, 32,  256, 0, 0);
  var_w_prep<<<dim3(16, 4), blk, 0, stream>>>(vWa, varw, 0);
  var_w_prep<<<dim3(16, 4), blk, 0, stream>>>(vWi, varw, 4);
  var_wglu_prep<<<dim3(16, 8), blk, 0, stream>>>(vWglu, varw);

  gemm1<<<dim3(256), blk, 0, stream>>>(x, ctx, bt1, jba, jbskip, a_bf, skipf);
  gemm_i<<<dim3(256), blk, 0, stream>>>(a_bf, wiT, jbi, i_bf);
  joint_tail<<<dim3(2048), blk, 0, stream>>>(i_bf, wgluT, jbglu, skipf, jlng, jlnb,
                                             out + (size_t)8192 * 256);

  hipFuncSetAttribute((const void*)var_chain, hipFuncAttributeMaxDynamicSharedMemorySize, 102912);
  var_chain<<<dim3(128, 2), dim3(512), 102912, stream>>>(x, varw, vba, vbi, vbglu,
                                                         vlng, vlnb,
                                                         out + (size_t)8192 * 256, out);
}

// Round 4
// 526.416 us; speedup vs baseline: 1.5428x; 1.0773x over previous
//
#include <hip/hip_runtime.h>

typedef unsigned short u16;
typedef __attribute__((ext_vector_type(8))) __bf16 bf16x8;
typedef __attribute__((ext_vector_type(4))) float f32x4;
typedef __attribute__((ext_vector_type(8))) u16 u16x8;

__device__ __forceinline__ u16 f2b(float f) {
  union { float f; unsigned u; } v; v.f = f;
  return (u16)((v.u + 0x7fffu + ((v.u >> 16) & 1u)) >> 16);
}
__device__ __forceinline__ float b2f(u16 h) {
  union { unsigned u; float f; } v; v.u = ((unsigned)h) << 16;
  return v.f;
}
__device__ __forceinline__ f32x4 mfma16(bf16x8 a, bf16x8 b, f32x4 c) {
  return __builtin_amdgcn_mfma_f32_16x16x32_bf16(a, b, c, 0, 0, 0);
}
__device__ __forceinline__ void gl_lds16(const void* g, void* l) {
  __builtin_amdgcn_global_load_lds(
      (const __attribute__((address_space(1))) void*)g,
      (__attribute__((address_space(3))) void*)l, 16, 0, 0);
}
__device__ __forceinline__ u16x8 cvt8(float4 a, float4 b) {
  u16x8 o;
  o[0] = f2b(a.x); o[1] = f2b(a.y); o[2] = f2b(a.z); o[3] = f2b(a.w);
  o[4] = f2b(b.x); o[5] = f2b(b.y); o[6] = f2b(b.z); o[7] = f2b(b.w);
  return o;
}

// ---------------- weight transpose+cast: src f32 [R,C] -> dst bf16 [C][R] (linear) ----------
__global__ __launch_bounds__(256) void transpose_cast(
    const float* __restrict__ src, u16* __restrict__ dst,
    int R, int C, int dstStride, long srcBatch, long dstBatch)
{
  __shared__ float tile[32][33];
  src += (long)blockIdx.z * srcBatch;
  dst += (long)blockIdx.z * dstBatch;
  const int c0 = blockIdx.x * 32, r0 = blockIdx.y * 32;
  const int tx = threadIdx.x & 31, ty = threadIdx.x >> 5;
  for (int i = ty; i < 32; i += 8) {
    int r = r0 + i, cc = c0 + tx;
    if (r < R && cc < C) tile[i][tx] = src[(long)r * C + cc];
  }
  __syncthreads();
  for (int i = ty; i < 32; i += 8) {
    int cc = c0 + i, r = r0 + tx;
    if (cc < C && r < R) dst[(long)cc * dstStride + r] = f2b(tile[tx][i]);
  }
}

// ---- var Wa/Wi -> pre-swizzled 32KB tiles: per (v,kc): [256 n][64 k2], chunk = n*8 + ((k2/8)^(n&7))
__global__ __launch_bounds__(256) void var_w_prep(
    const float* __restrict__ W, u16* __restrict__ dstbase, int rbase)
{
  const int v = blockIdx.x;   // 16
  const int kc = blockIdx.y;  // 4
  const int n = threadIdx.x;  // 256
  const float* src = W + (size_t)v * 65536 + (size_t)kc * 64 * 256 + n;
  u16* dst = dstbase + (size_t)v * 262144 + (size_t)(rbase + kc) * 16384;
#pragma unroll
  for (int l = 0; l < 8; ++l) {
    u16x8 o;
#pragma unroll
    for (int e = 0; e < 8; ++e) o[e] = f2b(src[(l * 8 + e) * 256]);
    const int chunk = n * 8 + (l ^ (n & 7));
    *(u16x8*)&dst[chunk * 8] = o;
  }
}

// ---- var Wglu -> tiles: per (v,kc): [512 n][32 k2], chunk = (n>>1)*8 + (((n&1)*4 + k2/8) ^ ((n>>1)&7))
__global__ __launch_bounds__(256) void var_wglu_prep(
    const float* __restrict__ W, u16* __restrict__ dstbase)
{
  const int v = blockIdx.x;   // 16
  const int kc = blockIdx.y;  // 8
  u16* dst = dstbase + (size_t)v * 262144 + (size_t)(8 + kc) * 16384;
#pragma unroll
  for (int half = 0; half < 2; ++half) {
    const int n = threadIdx.x + half * 256;
    const float* src = W + (size_t)v * 131072 + (size_t)kc * 32 * 512 + n;
    const int s = n >> 1;
#pragma unroll
    for (int l = 0; l < 4; ++l) {
      u16x8 o;
#pragma unroll
      for (int e = 0; e < 8; ++e) o[e] = f2b(src[(l * 8 + e) * 512]);
      const int chunk = s * 8 + ((((n & 1) * 4 + l)) ^ (s & 7));
      *(u16x8*)&dst[chunk * 8] = o;
    }
  }
}

// ---------------- gemm1: [x|ctx] @ [WaT|WcT ; WskipT|0]^T -> a (elu, bf16), skip (f32) ----
#define K1TOT 4352
__global__ __launch_bounds__(256, 3) void gemm1(
    const float* __restrict__ x, const float* __restrict__ ctx,
    const u16* __restrict__ bt1, const float* __restrict__ ba,
    const float* __restrict__ bskip, u16* __restrict__ a_bf, float* __restrict__ skip_f)
{
  __shared__ u16 As[32 * 64];
  __shared__ u16 Bs[288 * 64];
  const int tid = threadIdx.x;
  const int n0 = blockIdx.x * 32;
  const int w = tid >> 6, lane = tid & 63;
  const int q = lane >> 4, c = lane & 15;
  const int rt = w & 1, cg = w >> 1;
  const int t0 = cg ? 9 : 0;
  const int nt = cg ? 8 : 9;

  f32x4 acc[9];
#pragma unroll
  for (int i = 0; i < 9; ++i) acc[i] = f32x4{0.f, 0.f, 0.f, 0.f};

  const int sr = tid >> 3, sp = tid & 7;
  const int sl = sp ^ (sr & 7);

  for (int kb = 0; kb < K1TOT; kb += 64) {
    { // A stage: linear LDS write, column-permuted source (swizzle baked in)
      const float* s = (kb < 4096)
          ? (x + (size_t)(n0 + sr) * 4096 + kb + sl * 8)
          : (ctx + (size_t)(n0 + sr) * 256 + (kb - 4096) + sl * 8);
      float4 v0 = ((const float4*)s)[0];
      float4 v1 = ((const float4*)s)[1];
      *(u16x8*)&As[tid * 8] = cvt8(v0, v1);
    }
    // B stage: async global->LDS, linear dst, permuted per-lane src
#pragma unroll
    for (int i = 0; i < 9; ++i) {
      const int cb = (i * 4 + w) * 64;
      const int cid = cb + lane;
      const int row = cid >> 3, p = cid & 7;
      const int l = p ^ (row & 7);
      const u16* src = (row < 272) ? (bt1 + (size_t)row * K1TOT + kb + l * 8) : bt1;
      gl_lds16(src, &Bs[cb * 8]);
    }
    __syncthreads();
#pragma unroll
    for (int kk = 0; kk < 2; ++kk) {
      const int arow = rt * 16 + c;
      bf16x8 af = *(const bf16x8*)&As[(arow * 64 + kk * 32 + q * 8) ^ ((arow & 7) << 3)];
#pragma unroll
      for (int ti = 0; ti < 9; ++ti) {
        if (ti < nt) {
          const int n16 = (t0 + ti) * 16 + c;
          bf16x8 bfr = *(const bf16x8*)&Bs[(n16 * 64 + kk * 32 + q * 8) ^ ((n16 & 7) << 3)];
          acc[ti] = mfma16(af, bfr, acc[ti]);
        }
      }
    }
    __syncthreads();
  }
#pragma unroll
  for (int ti = 0; ti < 9; ++ti) {
    if (ti < nt) {
      const int col = (t0 + ti) * 16 + c;
#pragma unroll
      for (int j = 0; j < 4; ++j) {
        const long n = n0 + rt * 16 + q * 4 + j;
        float vv = acc[ti][j];
        if (col < 256) {
          vv += ba[col];
          vv = vv > 0.f ? vv : expm1f(vv);
          a_bf[n * 256 + col] = f2b(vv);
        } else {
          skip_f[n * 16 + (col - 256)] = vv + bskip[col - 256];
        }
      }
    }
  }
}

// ---------------- gemm_i: i = a @ Wi + bi -> bf16 ----------------
__global__ __launch_bounds__(256, 3) void gemm_i(
    const u16* __restrict__ a_bf, const u16* __restrict__ wiT,
    const float* __restrict__ bi, u16* __restrict__ i_bf)
{
  __shared__ u16 As[32 * 64];
  __shared__ u16 Bs[256 * 64];
  const int tid = threadIdx.x;
  const int n0 = blockIdx.x * 32;
  const int w = tid >> 6, lane = tid & 63;
  const int q = lane >> 4, c = lane & 15;
  const int rt = w & 1, cg = w >> 1;

  f32x4 acc[8];
#pragma unroll
  for (int i = 0; i < 8; ++i) acc[i] = f32x4{0.f, 0.f, 0.f, 0.f};

  for (int kb = 0; kb < 256; kb += 64) {
    { // A via global_load_lds (a_bf linear, permuted src)
      const int row = tid >> 3, p = tid & 7;
      const int l = p ^ (row & 7);
      gl_lds16(a_bf + (size_t)(n0 + row) * 256 + kb + l * 8, &As[w * 512]);
    }
#pragma unroll
    for (int i = 0; i < 8; ++i) {
      const int cb = (i * 4 + w) * 64;
      const int cid = cb + lane;
      const int row = cid >> 3, p = cid & 7;
      const int l = p ^ (row & 7);
      gl_lds16(wiT + (size_t)row * 256 + kb + l * 8, &Bs[cb * 8]);
    }
    __syncthreads();
#pragma unroll
    for (int kk = 0; kk < 2; ++kk) {
      const int arow = rt * 16 + c;
      bf16x8 af = *(const bf16x8*)&As[(arow * 64 + kk * 32 + q * 8) ^ ((arow & 7) << 3)];
#pragma unroll
      for (int ti = 0; ti < 8; ++ti) {
        const int n16 = (cg * 8 + ti) * 16 + c;
        bf16x8 bfr = *(const bf16x8*)&Bs[(n16 * 64 + kk * 32 + q * 8) ^ ((n16 & 7) << 3)];
        acc[ti] = mfma16(af, bfr, acc[ti]);
      }
    }
    __syncthreads();
  }
#pragma unroll
  for (int ti = 0; ti < 8; ++ti) {
    const int col = (cg * 8 + ti) * 16 + c;
    const float bb = bi[col];
#pragma unroll
    for (int j = 0; j < 4; ++j) {
      const long n = n0 + rt * 16 + q * 4 + j;
      i_bf[n * 256 + col] = f2b(acc[ti][j] + bb);
    }
  }
}

// ---------------- joint tail: g = i@Wglu; GLU; +skip; LN(16); softmax -> sw ----------------
__global__ __launch_bounds__(256) void joint_tail(
    const u16* __restrict__ i_bf, const u16* __restrict__ wgluT,
    const float* __restrict__ bglu, const float* __restrict__ skip_f,
    const float* __restrict__ lng, const float* __restrict__ lnb,
    float* __restrict__ swout)
{
  __shared__ float wlds[32 * 257];
  __shared__ float ilds[4][256];
  const int tid = threadIdx.x;
  for (int jj = 0; jj < 32; ++jj) wlds[jj * 257 + tid] = b2f(wgluT[jj * 256 + tid]);
  const int w = tid >> 6, lane = tid & 63;
  const long n = (long)blockIdx.x * 4 + w;
  {
    const u16* src = i_bf + n * 256 + lane * 4;
    float4 f;
    f.x = b2f(src[0]); f.y = b2f(src[1]); f.z = b2f(src[2]); f.w = b2f(src[3]);
    *(float4*)&ilds[w][lane * 4] = f;
  }
  __syncthreads();
  const int cc32 = lane & 31;
  const int k0 = (lane >> 5) * 128;
  float acc = 0.f;
  for (int k = 0; k < 128; ++k) acc += ilds[w][k0 + k] * wlds[cc32 * 257 + k0 + k];
  acc += __shfl_xor(acc, 32, 64);
  const float gfull = acc + bglu[cc32];
  const int cc = lane & 15;
  const float g1 = __shfl(gfull, cc, 64);
  const float g2 = __shfl(gfull, cc + 16, 64);
  const float glu = g1 / (1.f + __expf(-g2));
  const float y = glu + skip_f[n * 16 + cc];
  float s = y, ss = y * y;
#pragma unroll
  for (int d = 1; d < 16; d <<= 1) { s += __shfl_xor(s, d, 64); ss += __shfl_xor(ss, d, 64); }
  const float m = s * (1.f / 16.f);
  const float var = ss * (1.f / 16.f) - m * m;
  const float t = (y - m) * rsqrtf(var + 1e-5f) * lng[cc] + lnb[cc];
  float mx = t;
#pragma unroll
  for (int d = 1; d < 16; d <<= 1) mx = fmaxf(mx, __shfl_xor(mx, d, 64));
  const float e = __expf(t - mx);
  float es = e;
#pragma unroll
  for (int d = 1; d < 16; d <<= 1) es += __shfl_xor(es, d, 64);
  if (lane < 16) swout[n * 16 + lane] = e / es;
}

// ---------------- per-variable fused chain (M=64, 4 vars/block, 2 blocks/CU) --------------
// grid (4, 128): flat = x + 4y -> XCD = x + (y&1)*4, so each XCD serves ONE var-group
// (2 MB weights, L2-resident). Single xt1 buffer: x -> av -> iv in place. Residual re-read
// from global. Single-buffer wt staging, R3-proven barrier structure.
__global__ __launch_bounds__(512, 4) void var_chain(
    const float* __restrict__ x, const u16* __restrict__ varw,
    const float* __restrict__ vba, const float* __restrict__ vbi,
    const float* __restrict__ vbglu, const float* __restrict__ vlng,
    const float* __restrict__ vlnb, const float* __restrict__ sw,
    float* __restrict__ out)
{
  extern __shared__ u16 smem[];
  u16* const xt1 = smem;                       // 16384 u16 (32KB): x, then av, then iv
  u16* const wt  = smem + 16384;               // 32KB weight tile (single buffer)
  float* const red   = (float*)(smem + 32768); // 64*16 floats (4KB)
  float* const muinv = red + 1024;             // 64*2 floats (0.5KB)

  const int tid = threadIdx.x;
  const int w = tid >> 6, lane = tid & 63;
  const int q = lane >> 4, c = lane & 15;
  const int rt0 = (w & 1) << 1, cg = w >> 1;
  const int vbase = blockIdx.x * 4;
  const int n0 = blockIdx.y * 64;

  f32x4 outacc[4][2];
#pragma unroll
  for (int p = 0; p < 4; ++p)
#pragma unroll
    for (int u = 0; u < 2; ++u) outacc[p][u] = f32x4{0.f, 0.f, 0.f, 0.f};

  for (int vi = 0; vi < 4; ++vi) {
    const int v = vbase + vi;
    const u16* vtiles = varw + (size_t)v * 262144;

    // ---- write xt1 = x tile (linear chunks; source columns pre-permuted for swizzle) ----
#pragma unroll
    for (int jj = 0; jj < 4; ++jj) {
      const int cid = jj * 512 + tid;
      const int r = cid >> 5, p = cid & 31;
      const int l = (p & 24) | ((p & 7) ^ (r & 7));
      const float* s = x + (size_t)(n0 + r) * 4096 + (size_t)v * 256 + l * 8;
      float4 v0 = ((const float4*)s)[0];
      float4 v1 = ((const float4*)s)[1];
      *(u16x8*)&xt1[cid * 8] = cvt8(v0, v1);
    }
    __syncthreads();  // xt1(x) visible

    f32x4 acc2[2][4];
#pragma unroll
    for (int p = 0; p < 2; ++p)
#pragma unroll
      for (int ti = 0; ti < 4; ++ti) acc2[p][ti] = f32x4{0.f, 0.f, 0.f, 0.f};

    // ---- m1: av = elu(x @ WaT + ba) ----
    for (int kc = 0; kc < 4; ++kc) {
      {
        const u16* tb = vtiles + (size_t)kc * 16384;
#pragma unroll
        for (int i = 0; i < 4; ++i) {
          const int cb = (i * 8 + w) * 64;
          gl_lds16(tb + (size_t)(cb + lane) * 8, wt + (size_t)cb * 8);
        }
      }
      __syncthreads();  // stage complete
#pragma unroll
      for (int kk = 0; kk < 2; ++kk) {
        const int r0 = rt0 * 16 + c, r1 = (rt0 + 1) * 16 + c;
        bf16x8 a0 = *(const bf16x8*)&xt1[(r0 * 256 + kc * 64 + kk * 32 + q * 8) ^ ((r0 & 7) << 3)];
        bf16x8 a1 = *(const bf16x8*)&xt1[(r1 * 256 + kc * 64 + kk * 32 + q * 8) ^ ((r1 & 7) << 3)];
#pragma unroll
        for (int ti = 0; ti < 4; ++ti) {
          const int n16 = (cg * 4 + ti) * 16 + c;
          bf16x8 b = *(const bf16x8*)&wt[(n16 * 64 + kk * 32 + q * 8) ^ ((n16 & 7) << 3)];
          acc2[0][ti] = mfma16(a0, b, acc2[0][ti]);
          acc2[1][ti] = mfma16(a1, b, acc2[1][ti]);
        }
      }
      __syncthreads();  // reads complete before next stage overwrites wt
    }
    // all m1 reads of xt1(x) done -> overwrite with av
#pragma unroll
    for (int p = 0; p < 2; ++p)
#pragma unroll
      for (int ti = 0; ti < 4; ++ti) {
        const int col = (cg * 4 + ti) * 16 + c;
        const float bb = vba[v * 256 + col];
#pragma unroll
        for (int j = 0; j < 4; ++j) {
          const int row = (rt0 + p) * 16 + q * 4 + j;
          float vv = acc2[p][ti][j] + bb;
          vv = vv > 0.f ? vv : expm1f(vv);
          xt1[(row * 256 + col) ^ ((row & 7) << 3)] = f2b(vv);
        }
      }
    __syncthreads();  // xt1(av) visible

    // ---- m2: iv = av @ WiT + bi ----
#pragma unroll
    for (int p = 0; p < 2; ++p)
#pragma unroll
      for (int ti = 0; ti < 4; ++ti) acc2[p][ti] = f32x4{0.f, 0.f, 0.f, 0.f};
    for (int kc = 0; kc < 4; ++kc) {
      {
        const u16* tb = vtiles + (size_t)(4 + kc) * 16384;
#pragma unroll
        for (int i = 0; i < 4; ++i) {
          const int cb = (i * 8 + w) * 64;
          gl_lds16(tb + (size_t)(cb + lane) * 8, wt + (size_t)cb * 8);
        }
      }
      __syncthreads();
#pragma unroll
      for (int kk = 0; kk < 2; ++kk) {
        const int r0 = rt0 * 16 + c, r1 = (rt0 + 1) * 16 + c;
        bf16x8 a0 = *(const bf16x8*)&xt1[(r0 * 256 + kc * 64 + kk * 32 + q * 8) ^ ((r0 & 7) << 3)];
        bf16x8 a1 = *(const bf16x8*)&xt1[(r1 * 256 + kc * 64 + kk * 32 + q * 8) ^ ((r1 & 7) << 3)];
#pragma unroll
        for (int ti = 0; ti < 4; ++ti) {
          const int n16 = (cg * 4 + ti) * 16 + c;
          bf16x8 b = *(const bf16x8*)&wt[(n16 * 64 + kk * 32 + q * 8) ^ ((n16 & 7) << 3)];
          acc2[0][ti] = mfma16(a0, b, acc2[0][ti]);
          acc2[1][ti] = mfma16(a1, b, acc2[1][ti]);
        }
      }
      __syncthreads();
    }
    // all m2 reads of xt1(av) done -> overwrite with iv
#pragma unroll
    for (int p = 0; p < 2; ++p)
#pragma unroll
      for (int ti = 0; ti < 4; ++ti) {
        const int col = (cg * 4 + ti) * 16 + c;
        const float bb = vbi[v * 256 + col];
#pragma unroll
        for (int j = 0; j < 4; ++j) {
          const int row = (rt0 + p) * 16 + q * 4 + j;
          xt1[(row * 256 + col) ^ ((row & 7) << 3)] = f2b(acc2[p][ti][j] + bb);
        }
      }
    __syncthreads();  // xt1(iv) visible

    // ---- m3: gv = iv @ WgluT (N=512) ----
    f32x4 acc3[4][4];
#pragma unroll
    for (int p = 0; p < 4; ++p)
#pragma unroll
      for (int u = 0; u < 4; ++u) acc3[p][u] = f32x4{0.f, 0.f, 0.f, 0.f};
    for (int kc = 0; kc < 8; ++kc) {
      {
        const u16* tb = vtiles + (size_t)(8 + kc) * 16384;
#pragma unroll
        for (int i = 0; i < 4; ++i) {
          const int cb = (i * 8 + w) * 64;
          gl_lds16(tb + (size_t)(cb + lane) * 8, wt + (size_t)cb * 8);
        }
      }
      __syncthreads();  // stage complete
      bf16x8 a[4];
#pragma unroll
      for (int p = 0; p < 4; ++p) {
        const int r = p * 16 + c;
        a[p] = *(const bf16x8*)&xt1[(r * 256 + kc * 32 + q * 8) ^ ((r & 7) << 3)];
      }
#pragma unroll
      for (int u = 0; u < 4; ++u) {
        const int gt = 2 * w + (u & 1) + (u >> 1) * 16;
        const int n = gt * 16 + c;
        const int idx = (n >> 1) * 64 + ((((n & 1) * 4 + q) ^ ((n >> 1) & 7)) * 8);
        bf16x8 b = *(const bf16x8*)&wt[idx];
#pragma unroll
        for (int p = 0; p < 4; ++p) acc3[p][u] = mfma16(a[p], b, acc3[p][u]);
      }
      __syncthreads();  // reads complete before next stage
    }

    // ---- epilogue: GLU + residual (from global) + LN + weighted accumulate ----
    float b1v[2], b2v[2], lgv[2], lbv[2];
#pragma unroll
    for (int u01 = 0; u01 < 2; ++u01) {
      const int col = w * 32 + u01 * 16 + c;
      b1v[u01] = vbglu[v * 512 + col];
      b2v[u01] = vbglu[v * 512 + 256 + col];
      lgv[u01] = vlng[v * 256 + col];
      lbv[u01] = vlnb[v * 256 + col];
    }
    float rs[4][4], rss[4][4];
#pragma unroll
    for (int p = 0; p < 4; ++p)
#pragma unroll
      for (int j = 0; j < 4; ++j) { rs[p][j] = 0.f; rss[p][j] = 0.f; }
#pragma unroll
    for (int h = 0; h < 2; ++h) {  // two halves of 2 row-groups: bounds transient regs to 16
      float resid[2][2][4];
#pragma unroll
      for (int pp = 0; pp < 2; ++pp)
#pragma unroll
        for (int u01 = 0; u01 < 2; ++u01) {
          const int col = w * 32 + u01 * 16 + c;
#pragma unroll
          for (int j = 0; j < 4; ++j) {
            const int row = (h * 2 + pp) * 16 + q * 4 + j;
            resid[pp][u01][j] = x[(size_t)(n0 + row) * 4096 + (size_t)v * 256 + col];
          }
        }
#pragma unroll
      for (int pp = 0; pp < 2; ++pp) {
        const int p = h * 2 + pp;
#pragma unroll
        for (int u01 = 0; u01 < 2; ++u01) {
#pragma unroll
          for (int j = 0; j < 4; ++j) {
            const float g1 = acc3[p][u01][j] + b1v[u01];
            const float g2 = acc3[p][u01 + 2][j] + b2v[u01];
            const float glu = g1 / (1.f + __expf(-g2));
            const float r = glu + resid[pp][u01][j];
            acc3[p][u01][j] = r;
            rs[p][j] += r; rss[p][j] += r * r;
          }
        }
      }
    }
#pragma unroll
    for (int p = 0; p < 4; ++p)
#pragma unroll
      for (int j = 0; j < 4; ++j)
#pragma unroll
        for (int d = 1; d < 16; d <<= 1) {
          rs[p][j]  += __shfl_xor(rs[p][j], d, 64);
          rss[p][j] += __shfl_xor(rss[p][j], d, 64);
        }
    if (c == 0) {
#pragma unroll
      for (int p = 0; p < 4; ++p)
#pragma unroll
        for (int j = 0; j < 4; ++j) {
          const int row = p * 16 + q * 4 + j;
          red[row * 16 + w * 2]     = rs[p][j];
          red[row * 16 + w * 2 + 1] = rss[p][j];
        }
    }
    __syncthreads();
    if (tid < 64) {
      float ms = 0.f, vs = 0.f;
#pragma unroll
      for (int ww = 0; ww < 8; ++ww) { ms += red[tid * 16 + ww * 2]; vs += red[tid * 16 + ww * 2 + 1]; }
      const float mm = ms * (1.f / 256.f);
      muinv[tid * 2]     = mm;
      muinv[tid * 2 + 1] = rsqrtf(vs * (1.f / 256.f) - mm * mm + 1e-5f);
    }
    __syncthreads();
#pragma unroll
    for (int p = 0; p < 4; ++p) {
#pragma unroll
      for (int j = 0; j < 4; ++j) {
        const int row = p * 16 + q * 4 + j;
        const float mu = muinv[row * 2], inv = muinv[row * 2 + 1];
        const float wv = sw[(size_t)(n0 + row) * 16 + v];
#pragma unroll
        for (int u01 = 0; u01 < 2; ++u01) {
          const float tv = (acc3[p][u01][j] - mu) * inv * lgv[u01] + lbv[u01];
          outacc[p][u01][j] += tv * wv;
        }
      }
    }
    __syncthreads();  // muinv/red reads done before next var reuses LDS
  }

#pragma unroll
  for (int p = 0; p < 4; ++p)
#pragma unroll
    for (int u01 = 0; u01 < 2; ++u01) {
      const int col = w * 32 + u01 * 16 + c;
#pragma unroll
      for (int j = 0; j < 4; ++j) {
        const int row = p * 16 + q * 4 + j;
        atomicAdd(&out[(size_t)(n0 + row) * 256 + col], outacc[p][u01][j]);
      }
    }
}

extern "C" void kernel_launch(void* const* d_in, const int* in_sizes, int n_in,
                              void* d_out, int out_size, void* d_ws, size_t ws_size,
                              hipStream_t stream) {
  const float* x     = (const float*)d_in[0];
  const float* ctx   = (const float*)d_in[1];
  const float* jWa   = (const float*)d_in[2];
  const float* jba   = (const float*)d_in[3];
  const float* jWc   = (const float*)d_in[4];
  const float* jWi   = (const float*)d_in[5];
  const float* jbi   = (const float*)d_in[6];
  const float* jWglu = (const float*)d_in[7];
  const float* jbglu = (const float*)d_in[8];
  const float* jWskip= (const float*)d_in[9];
  const float* jbskip= (const float*)d_in[10];
  const float* jlng  = (const float*)d_in[11];
  const float* jlnb  = (const float*)d_in[12];
  const float* vWa   = (const float*)d_in[13];
  const float* vba   = (const float*)d_in[14];
  const float* vWi   = (const float*)d_in[15];
  const float* vbi   = (const float*)d_in[16];
  const float* vWglu = (const float*)d_in[17];
  const float* vbglu = (const float*)d_in[18];
  const float* vlng  = (const float*)d_in[19];
  const float* vlnb  = (const float*)d_in[20];
  float* out = (float*)d_out;

  char* ws = (char*)d_ws;
  size_t off = 0;
  auto alloc = [&](size_t bytes) { void* p = ws + off; off += (bytes + 255) & ~(size_t)255; return p; };
  u16* bt1     = (u16*)alloc((size_t)272 * 4352 * 2);
  u16* wiT     = (u16*)alloc((size_t)256 * 256 * 2);
  u16* wgluT   = (u16*)alloc((size_t)32 * 256 * 2);
  u16* varw    = (u16*)alloc((size_t)16 * 262144 * 2);   // 16 vars x 16 tiles x 32KB
  u16* a_bf    = (u16*)alloc((size_t)8192 * 256 * 2);
  u16* i_bf    = (u16*)alloc((size_t)8192 * 256 * 2);
  float* skipf = (float*)alloc((size_t)8192 * 16 * 4);

  hipMemsetAsync(bt1, 0, (size_t)272 * 4352 * 2, stream);
  hipMemsetAsync(out, 0, (size_t)8192 * 256 * 4, stream);

  dim3 blk(256);
  transpose_cast<<<dim3(8, 128, 1),  blk, 0, stream>>>(jWa,   bt1,              4096, 256, 4352, 0, 0);
  transpose_cast<<<dim3(8, 8, 1),    blk, 0, stream>>>(jWc,   bt1 + 4096,       256,  256, 4352, 0, 0);
  transpose_cast<<<dim3(1, 128, 1),  blk, 0, stream>>>(jWskip,bt1 + 256 * 4352, 4096, 16,  4352, 0, 0);
  transpose_cast<<<dim3(8, 8, 1),    blk, 0, stream>>>(jWi,   wiT,   256, 256, 256, 0, 0);
  transpose_cast<<<dim3(1, 8, 1),    blk, 0, stream>>>(jWglu, wgluT, 256, 32,  256, 0, 0);
  var_w_prep<<<dim3(16, 4), blk, 0, stream>>>(vWa, varw, 0);
  var_w_prep<<<dim3(16, 4), blk, 0, stream>>>(vWi, varw, 4);
  var_wglu_prep<<<dim3(16, 8), blk, 0, stream>>>(vWglu, varw);

  gemm1<<<dim3(256), blk, 0, stream>>>(x, ctx, bt1, jba, jbskip, a_bf, skipf);
  gemm_i<<<dim3(256), blk, 0, stream>>>(a_bf, wiT, jbi, i_bf);
  joint_tail<<<dim3(2048), blk, 0, stream>>>(i_bf, wgluT, jbglu, skipf, jlng, jlnb,
                                             out + (size_t)8192 * 256);

  hipFuncSetAttribute((const void*)var_chain, hipFuncAttributeMaxDynamicSharedMemorySize, 70144);
  var_chain<<<dim3(4, 128), dim3(512), 70144, stream>>>(x, varw, vba, vbi, vbglu,
                                                        vlng, vlnb,
                                                        out + (size_t)8192 * 256, out);
}

// Round 5
// 479.345 us; speedup vs baseline: 1.6943x; 1.0982x over previous
//
#include <hip/hip_runtime.h>

typedef unsigned short u16;
typedef __attribute__((ext_vector_type(8))) __bf16 bf16x8;
typedef __attribute__((ext_vector_type(4))) float f32x4;
typedef __attribute__((ext_vector_type(8))) u16 u16x8;

__device__ __forceinline__ u16 f2b(float f) {
  union { float f; unsigned u; } v; v.f = f;
  return (u16)((v.u + 0x7fffu + ((v.u >> 16) & 1u)) >> 16);
}
__device__ __forceinline__ float b2f(u16 h) {
  union { unsigned u; float f; } v; v.u = ((unsigned)h) << 16;
  return v.f;
}
__device__ __forceinline__ f32x4 mfma16(bf16x8 a, bf16x8 b, f32x4 c) {
  return __builtin_amdgcn_mfma_f32_16x16x32_bf16(a, b, c, 0, 0, 0);
}
__device__ __forceinline__ void gl_lds16(const void* g, void* l) {
  __builtin_amdgcn_global_load_lds(
      (const __attribute__((address_space(1))) void*)g,
      (__attribute__((address_space(3))) void*)l, 16, 0, 0);
}
__device__ __forceinline__ u16x8 cvt8(float4 a, float4 b) {
  u16x8 o;
  o[0] = f2b(a.x); o[1] = f2b(a.y); o[2] = f2b(a.z); o[3] = f2b(a.w);
  o[4] = f2b(b.x); o[5] = f2b(b.y); o[6] = f2b(b.z); o[7] = f2b(b.w);
  return o;
}

// ---------------- weight transpose+cast: src f32 [R,C] -> dst bf16 [C][R] (linear) ----------
__global__ __launch_bounds__(256) void transpose_cast(
    const float* __restrict__ src, u16* __restrict__ dst,
    int R, int C, int dstStride, long srcBatch, long dstBatch)
{
  __shared__ float tile[32][33];
  src += (long)blockIdx.z * srcBatch;
  dst += (long)blockIdx.z * dstBatch;
  const int c0 = blockIdx.x * 32, r0 = blockIdx.y * 32;
  const int tx = threadIdx.x & 31, ty = threadIdx.x >> 5;
  for (int i = ty; i < 32; i += 8) {
    int r = r0 + i, cc = c0 + tx;
    if (r < R && cc < C) tile[i][tx] = src[(long)r * C + cc];
  }
  __syncthreads();
  for (int i = ty; i < 32; i += 8) {
    int cc = c0 + i, r = r0 + tx;
    if (cc < C && r < R) dst[(long)cc * dstStride + r] = f2b(tile[tx][i]);
  }
}

// ---- var Wa/Wi -> pre-swizzled 32KB tiles: per (v,kc): [256 n][64 k2], chunk = n*8 + ((k2/8)^(n&7))
__global__ __launch_bounds__(256) void var_w_prep(
    const float* __restrict__ W, u16* __restrict__ dstbase, int rbase)
{
  const int v = blockIdx.x;   // 16
  const int kc = blockIdx.y;  // 4
  const int n = threadIdx.x;  // 256
  const float* src = W + (size_t)v * 65536 + (size_t)kc * 64 * 256 + n;
  u16* dst = dstbase + (size_t)v * 262144 + (size_t)(rbase + kc) * 16384;
#pragma unroll
  for (int l = 0; l < 8; ++l) {
    u16x8 o;
#pragma unroll
    for (int e = 0; e < 8; ++e) o[e] = f2b(src[(l * 8 + e) * 256]);
    const int chunk = n * 8 + (l ^ (n & 7));
    *(u16x8*)&dst[chunk * 8] = o;
  }
}

// ---- var Wglu -> tiles: per (v,kc): [512 n][32 k2], chunk = (n>>1)*8 + (((n&1)*4 + k2/8) ^ ((n>>1)&7))
__global__ __launch_bounds__(256) void var_wglu_prep(
    const float* __restrict__ W, u16* __restrict__ dstbase)
{
  const int v = blockIdx.x;   // 16
  const int kc = blockIdx.y;  // 8
  u16* dst = dstbase + (size_t)v * 262144 + (size_t)(8 + kc) * 16384;
#pragma unroll
  for (int half = 0; half < 2; ++half) {
    const int n = threadIdx.x + half * 256;
    const float* src = W + (size_t)v * 131072 + (size_t)kc * 32 * 512 + n;
    const int s = n >> 1;
#pragma unroll
    for (int l = 0; l < 4; ++l) {
      u16x8 o;
#pragma unroll
      for (int e = 0; e < 8; ++e) o[e] = f2b(src[(l * 8 + e) * 512]);
      const int chunk = s * 8 + ((((n & 1) * 4 + l)) ^ (s & 7));
      *(u16x8*)&dst[chunk * 8] = o;
    }
  }
}

// ---------------- gemm1: [x|ctx] @ [WaT|WcT ; WskipT|0]^T -> a (elu, bf16), skip (f32) ----
#define K1TOT 4352
__global__ __launch_bounds__(256, 3) void gemm1(
    const float* __restrict__ x, const float* __restrict__ ctx,
    const u16* __restrict__ bt1, const float* __restrict__ ba,
    const float* __restrict__ bskip, u16* __restrict__ a_bf, float* __restrict__ skip_f)
{
  __shared__ u16 As[32 * 64];
  __shared__ u16 Bs[288 * 64];
  const int tid = threadIdx.x;
  const int n0 = blockIdx.x * 32;
  const int w = tid >> 6, lane = tid & 63;
  const int q = lane >> 4, c = lane & 15;
  const int rt = w & 1, cg = w >> 1;
  const int t0 = cg ? 9 : 0;
  const int nt = cg ? 8 : 9;

  f32x4 acc[9];
#pragma unroll
  for (int i = 0; i < 9; ++i) acc[i] = f32x4{0.f, 0.f, 0.f, 0.f};

  const int sr = tid >> 3, sp = tid & 7;
  const int sl = sp ^ (sr & 7);

  for (int kb = 0; kb < K1TOT; kb += 64) {
    { // A stage: linear LDS write, column-permuted source (swizzle baked in)
      const float* s = (kb < 4096)
          ? (x + (size_t)(n0 + sr) * 4096 + kb + sl * 8)
          : (ctx + (size_t)(n0 + sr) * 256 + (kb - 4096) + sl * 8);
      float4 v0 = ((const float4*)s)[0];
      float4 v1 = ((const float4*)s)[1];
      *(u16x8*)&As[tid * 8] = cvt8(v0, v1);
    }
    // B stage: async global->LDS, linear dst, permuted per-lane src
#pragma unroll
    for (int i = 0; i < 9; ++i) {
      const int cb = (i * 4 + w) * 64;
      const int cid = cb + lane;
      const int row = cid >> 3, p = cid & 7;
      const int l = p ^ (row & 7);
      const u16* src = (row < 272) ? (bt1 + (size_t)row * K1TOT + kb + l * 8) : bt1;
      gl_lds16(src, &Bs[cb * 8]);
    }
    __syncthreads();
#pragma unroll
    for (int kk = 0; kk < 2; ++kk) {
      const int arow = rt * 16 + c;
      bf16x8 af = *(const bf16x8*)&As[(arow * 64 + kk * 32 + q * 8) ^ ((arow & 7) << 3)];
#pragma unroll
      for (int ti = 0; ti < 9; ++ti) {
        if (ti < nt) {
          const int n16 = (t0 + ti) * 16 + c;
          bf16x8 bfr = *(const bf16x8*)&Bs[(n16 * 64 + kk * 32 + q * 8) ^ ((n16 & 7) << 3)];
          acc[ti] = mfma16(af, bfr, acc[ti]);
        }
      }
    }
    __syncthreads();
  }
#pragma unroll
  for (int ti = 0; ti < 9; ++ti) {
    if (ti < nt) {
      const int col = (t0 + ti) * 16 + c;
#pragma unroll
      for (int j = 0; j < 4; ++j) {
        const long n = n0 + rt * 16 + q * 4 + j;
        float vv = acc[ti][j];
        if (col < 256) {
          vv += ba[col];
          vv = vv > 0.f ? vv : expm1f(vv);
          a_bf[n * 256 + col] = f2b(vv);
        } else {
          skip_f[n * 16 + (col - 256)] = vv + bskip[col - 256];
        }
      }
    }
  }
}

// ---------------- gemm_i: i = a @ Wi + bi -> bf16 ----------------
__global__ __launch_bounds__(256, 3) void gemm_i(
    const u16* __restrict__ a_bf, const u16* __restrict__ wiT,
    const float* __restrict__ bi, u16* __restrict__ i_bf)
{
  __shared__ u16 As[32 * 64];
  __shared__ u16 Bs[256 * 64];
  const int tid = threadIdx.x;
  const int n0 = blockIdx.x * 32;
  const int w = tid >> 6, lane = tid & 63;
  const int q = lane >> 4, c = lane & 15;
  const int rt = w & 1, cg = w >> 1;

  f32x4 acc[8];
#pragma unroll
  for (int i = 0; i < 8; ++i) acc[i] = f32x4{0.f, 0.f, 0.f, 0.f};

  for (int kb = 0; kb < 256; kb += 64) {
    { // A via global_load_lds (a_bf linear, permuted src)
      const int row = tid >> 3, p = tid & 7;
      const int l = p ^ (row & 7);
      gl_lds16(a_bf + (size_t)(n0 + row) * 256 + kb + l * 8, &As[w * 512]);
    }
#pragma unroll
    for (int i = 0; i < 8; ++i) {
      const int cb = (i * 4 + w) * 64;
      const int cid = cb + lane;
      const int row = cid >> 3, p = cid & 7;
      const int l = p ^ (row & 7);
      gl_lds16(wiT + (size_t)row * 256 + kb + l * 8, &Bs[cb * 8]);
    }
    __syncthreads();
#pragma unroll
    for (int kk = 0; kk < 2; ++kk) {
      const int arow = rt * 16 + c;
      bf16x8 af = *(const bf16x8*)&As[(arow * 64 + kk * 32 + q * 8) ^ ((arow & 7) << 3)];
#pragma unroll
      for (int ti = 0; ti < 8; ++ti) {
        const int n16 = (cg * 8 + ti) * 16 + c;
        bf16x8 bfr = *(const bf16x8*)&Bs[(n16 * 64 + kk * 32 + q * 8) ^ ((n16 & 7) << 3)];
        acc[ti] = mfma16(af, bfr, acc[ti]);
      }
    }
    __syncthreads();
  }
#pragma unroll
  for (int ti = 0; ti < 8; ++ti) {
    const int col = (cg * 8 + ti) * 16 + c;
    const float bb = bi[col];
#pragma unroll
    for (int j = 0; j < 4; ++j) {
      const long n = n0 + rt * 16 + q * 4 + j;
      i_bf[n * 256 + col] = f2b(acc[ti][j] + bb);
    }
  }
}

// ---------------- joint tail: g = i@Wglu; GLU; +skip; LN(16); softmax -> sw ----------------
__global__ __launch_bounds__(256) void joint_tail(
    const u16* __restrict__ i_bf, const u16* __restrict__ wgluT,
    const float* __restrict__ bglu, const float* __restrict__ skip_f,
    const float* __restrict__ lng, const float* __restrict__ lnb,
    float* __restrict__ swout)
{
  __shared__ float wlds[32 * 257];
  __shared__ float ilds[4][256];
  const int tid = threadIdx.x;
  for (int jj = 0; jj < 32; ++jj) wlds[jj * 257 + tid] = b2f(wgluT[jj * 256 + tid]);
  const int w = tid >> 6, lane = tid & 63;
  const long n = (long)blockIdx.x * 4 + w;
  {
    const u16* src = i_bf + n * 256 + lane * 4;
    float4 f;
    f.x = b2f(src[0]); f.y = b2f(src[1]); f.z = b2f(src[2]); f.w = b2f(src[3]);
    *(float4*)&ilds[w][lane * 4] = f;
  }
  __syncthreads();
  const int cc32 = lane & 31;
  const int k0 = (lane >> 5) * 128;
  float acc = 0.f;
  for (int k = 0; k < 128; ++k) acc += ilds[w][k0 + k] * wlds[cc32 * 257 + k0 + k];
  acc += __shfl_xor(acc, 32, 64);
  const float gfull = acc + bglu[cc32];
  const int cc = lane & 15;
  const float g1 = __shfl(gfull, cc, 64);
  const float g2 = __shfl(gfull, cc + 16, 64);
  const float glu = g1 / (1.f + __expf(-g2));
  const float y = glu + skip_f[n * 16 + cc];
  float s = y, ss = y * y;
#pragma unroll
  for (int d = 1; d < 16; d <<= 1) { s += __shfl_xor(s, d, 64); ss += __shfl_xor(ss, d, 64); }
  const float m = s * (1.f / 16.f);
  const float var = ss * (1.f / 16.f) - m * m;
  const float t = (y - m) * rsqrtf(var + 1e-5f) * lng[cc] + lnb[cc];
  float mx = t;
#pragma unroll
  for (int d = 1; d < 16; d <<= 1) mx = fmaxf(mx, __shfl_xor(mx, d, 64));
  const float e = __expf(t - mx);
  float es = e;
#pragma unroll
  for (int d = 1; d < 16; d <<= 1) es += __shfl_xor(es, d, 64);
  if (lane < 16) swout[n * 16 + lane] = e / es;
}

// ---------------- per-variable fused chain v3 ----------------
// M=128 rows, 1024 threads (16 waves: rt=w>>2 rows, cg=w&3 cols), 4 vars/block,
// grid (4, 64) -> XCD = bx + 4*(by&1): one var-group per XCD (2 MB weights L2-hot).
// 2-phase pipeline (guide T3 minimum recipe): STAGE(buf^1, t+1) issued BEFORE
// compute(buf); ONE __syncthreads() per tile (= vmcnt(0)+lgkmcnt(0)+barrier drain).
// Weight demand halves vs R4 (512 MB); per-stage MFMA work doubles.
__global__ __launch_bounds__(1024, 1) void var_chain(
    const float* __restrict__ x, const u16* __restrict__ varw,
    const float* __restrict__ vba, const float* __restrict__ vbi,
    const float* __restrict__ vbglu, const float* __restrict__ vlng,
    const float* __restrict__ vlnb, const float* __restrict__ sw,
    float* __restrict__ out)
{
  extern __shared__ u16 smem[];
  u16* const xt1 = smem;                        // 32768 u16 (64KB): x -> av -> iv in place
  u16* const wtb = smem + 32768;                // 2 x 16384 u16 (2 x 32KB) weight dbuf
  float* const red   = (float*)(smem + 65536);  // [128][4][2] floats (4KB)
  float* const muinv = red + 1024;              // [128][2] floats (1KB)

  const int tid = threadIdx.x;
  const int w = tid >> 6, lane = tid & 63;
  const int q = lane >> 4, c = lane & 15;
  const int rt = w >> 2, cg = w & 3;
  const int vbase = blockIdx.x * 4;
  const int n0 = blockIdx.y * 128;

  f32x4 outacc[2][4];
#pragma unroll
  for (int p = 0; p < 2; ++p)
#pragma unroll
    for (int u = 0; u < 4; ++u) outacc[p][u] = f32x4{0.f, 0.f, 0.f, 0.f};

  // STAGE helper: stage 32KB tile tn into wtb[b]
  auto STAGE = [&](int b, int tn) {
    const u16* tb = varw + (size_t)(vbase + (tn >> 4)) * 262144 + (size_t)(tn & 15) * 16384;
    u16* dst = wtb + (b << 14);
#pragma unroll
    for (int i = 0; i < 2; ++i) {
      const int cb = (i * 16 + w) * 64;
      gl_lds16(tb + (size_t)(cb + lane) * 8, dst + (size_t)cb * 8);
    }
  };

  int cur = 0;
  STAGE(0, 0);  // prologue: tile 0 in flight; drained by the var-start __syncthreads

  for (int vi = 0; vi < 4; ++vi) {
    const int v = vbase + vi;
    const int tb0 = vi * 16;

    // ---- write xt1 = x tile (linear chunks; source columns pre-permuted) ----
#pragma unroll
    for (int jj = 0; jj < 4; ++jj) {
      const int cid = jj * 1024 + tid;
      const int r = cid >> 5, p = cid & 31;
      const int l = (p & 24) | ((p & 7) ^ (r & 7));
      const float* s = x + (size_t)(n0 + r) * 4096 + (size_t)v * 256 + l * 8;
      float4 v0 = ((const float4*)s)[0];
      float4 v1 = ((const float4*)s)[1];
      *(u16x8*)&xt1[cid * 8] = cvt8(v0, v1);
    }
    __syncthreads();  // xt1(x) visible; tile tb0 staged (drained here or earlier)

    f32x4 acc2[2][4];
#pragma unroll
    for (int p = 0; p < 2; ++p)
#pragma unroll
      for (int ti = 0; ti < 4; ++ti) acc2[p][ti] = f32x4{0.f, 0.f, 0.f, 0.f};

    // ---- m1: av = elu(x @ WaT + ba), tiles tb0..tb0+3 ----
    for (int t = tb0; t < tb0 + 4; ++t) {
      const int tn = t + 1 < 64 ? t + 1 : 63;
      STAGE(cur ^ 1, tn);                     // next tile flies under compute
      const u16* wcur = wtb + (cur << 14);
      const int kc = t - tb0;
#pragma unroll
      for (int kk = 0; kk < 2; ++kk) {
        bf16x8 a[2];
#pragma unroll
        for (int p = 0; p < 2; ++p) {
          const int r = (rt * 2 + p) * 16 + c;
          a[p] = *(const bf16x8*)&xt1[(r * 256 + kc * 64 + kk * 32 + q * 8) ^ ((r & 7) << 3)];
        }
#pragma unroll
        for (int ti = 0; ti < 4; ++ti) {
          const int n16 = (cg * 4 + ti) * 16 + c;
          bf16x8 b = *(const bf16x8*)&wcur[(n16 * 64 + kk * 32 + q * 8) ^ ((n16 & 7) << 3)];
          acc2[0][ti] = mfma16(a[0], b, acc2[0][ti]);
          acc2[1][ti] = mfma16(a[1], b, acc2[1][ti]);
        }
      }
      __syncthreads();  // drains STAGE (vmcnt0) + all reads of cur consumed
      cur ^= 1;
    }
    // write av -> xt1
#pragma unroll
    for (int p = 0; p < 2; ++p)
#pragma unroll
      for (int ti = 0; ti < 4; ++ti) {
        const int col = (cg * 4 + ti) * 16 + c;
        const float bb = vba[v * 256 + col];
#pragma unroll
        for (int j = 0; j < 4; ++j) {
          const int row = (rt * 2 + p) * 16 + q * 4 + j;
          float vv = acc2[p][ti][j] + bb;
          vv = vv > 0.f ? vv : expm1f(vv);
          xt1[(row * 256 + col) ^ ((row & 7) << 3)] = f2b(vv);
        }
      }
    __syncthreads();  // xt1(av) visible

    // ---- m2: iv = av @ WiT + bi, tiles tb0+4..tb0+7 ----
#pragma unroll
    for (int p = 0; p < 2; ++p)
#pragma unroll
      for (int ti = 0; ti < 4; ++ti) acc2[p][ti] = f32x4{0.f, 0.f, 0.f, 0.f};
    for (int t = tb0 + 4; t < tb0 + 8; ++t) {
      const int tn = t + 1 < 64 ? t + 1 : 63;
      STAGE(cur ^ 1, tn);
      const u16* wcur = wtb + (cur << 14);
      const int kc = t - (tb0 + 4);
#pragma unroll
      for (int kk = 0; kk < 2; ++kk) {
        bf16x8 a[2];
#pragma unroll
        for (int p = 0; p < 2; ++p) {
          const int r = (rt * 2 + p) * 16 + c;
          a[p] = *(const bf16x8*)&xt1[(r * 256 + kc * 64 + kk * 32 + q * 8) ^ ((r & 7) << 3)];
        }
#pragma unroll
        for (int ti = 0; ti < 4; ++ti) {
          const int n16 = (cg * 4 + ti) * 16 + c;
          bf16x8 b = *(const bf16x8*)&wcur[(n16 * 64 + kk * 32 + q * 8) ^ ((n16 & 7) << 3)];
          acc2[0][ti] = mfma16(a[0], b, acc2[0][ti]);
          acc2[1][ti] = mfma16(a[1], b, acc2[1][ti]);
        }
      }
      __syncthreads();
      cur ^= 1;
    }
    // write iv -> xt1
#pragma unroll
    for (int p = 0; p < 2; ++p)
#pragma unroll
      for (int ti = 0; ti < 4; ++ti) {
        const int col = (cg * 4 + ti) * 16 + c;
        const float bb = vbi[v * 256 + col];
#pragma unroll
        for (int j = 0; j < 4; ++j) {
          const int row = (rt * 2 + p) * 16 + q * 4 + j;
          xt1[(row * 256 + col) ^ ((row & 7) << 3)] = f2b(acc2[p][ti][j] + bb);
        }
      }
    __syncthreads();  // xt1(iv) visible

    // ---- m3: gv = iv @ WgluT (N=512), tiles tb0+8..tb0+15 ----
    // wave cg owns col-tiles {cg*4+u, 16+cg*4+u}: g1 in acc3[*][0..3], g2 in acc3[*][4..7]
    f32x4 acc3[2][8];
#pragma unroll
    for (int p = 0; p < 2; ++p)
#pragma unroll
      for (int u = 0; u < 8; ++u) acc3[p][u] = f32x4{0.f, 0.f, 0.f, 0.f};
    for (int t = tb0 + 8; t < tb0 + 16; ++t) {
      const int tn = t + 1 < 64 ? t + 1 : 63;
      STAGE(cur ^ 1, tn);
      const u16* wcur = wtb + (cur << 14);
      const int kc = t - (tb0 + 8);
      bf16x8 a[2];
#pragma unroll
      for (int p = 0; p < 2; ++p) {
        const int r = (rt * 2 + p) * 16 + c;
        a[p] = *(const bf16x8*)&xt1[(r * 256 + kc * 32 + q * 8) ^ ((r & 7) << 3)];
      }
#pragma unroll
      for (int u = 0; u < 8; ++u) {
        const int ct = cg * 4 + (u & 3) + ((u >> 2) << 4);
        const int n = ct * 16 + c;
        const int idx = (n >> 1) * 64 + ((((n & 1) * 4 + q) ^ ((n >> 1) & 7)) * 8);
        bf16x8 b = *(const bf16x8*)&wcur[idx];
        acc3[0][u] = mfma16(a[0], b, acc3[0][u]);
        acc3[1][u] = mfma16(a[1], b, acc3[1][u]);
      }
      __syncthreads();
      cur ^= 1;
    }

    // ---- epilogue: GLU + residual (global) + LN + weighted accumulate ----
    float b1v[4], b2v[4], lgv[4], lbv[4];
#pragma unroll
    for (int u = 0; u < 4; ++u) {
      const int col = cg * 64 + u * 16 + c;
      b1v[u] = vbglu[v * 512 + col];
      b2v[u] = vbglu[v * 512 + 256 + col];
      lgv[u] = vlng[v * 256 + col];
      lbv[u] = vlnb[v * 256 + col];
    }
    float rs[2][4], rss[2][4];
#pragma unroll
    for (int p = 0; p < 2; ++p)
#pragma unroll
      for (int j = 0; j < 4; ++j) { rs[p][j] = 0.f; rss[p][j] = 0.f; }
#pragma unroll
    for (int p = 0; p < 2; ++p)
#pragma unroll
      for (int u = 0; u < 4; ++u) {
        const int col = cg * 64 + u * 16 + c;
#pragma unroll
        for (int j = 0; j < 4; ++j) {
          const int row = (rt * 2 + p) * 16 + q * 4 + j;
          const float g1 = acc3[p][u][j] + b1v[u];
          const float g2 = acc3[p][u + 4][j] + b2v[u];
          const float glu = g1 / (1.f + __expf(-g2));
          const float r = glu + x[(size_t)(n0 + row) * 4096 + (size_t)v * 256 + col];
          acc3[p][u][j] = r;
          rs[p][j] += r; rss[p][j] += r * r;
        }
      }
#pragma unroll
    for (int p = 0; p < 2; ++p)
#pragma unroll
      for (int j = 0; j < 4; ++j)
#pragma unroll
        for (int d = 1; d < 16; d <<= 1) {
          rs[p][j]  += __shfl_xor(rs[p][j], d, 64);
          rss[p][j] += __shfl_xor(rss[p][j], d, 64);
        }
    if (c == 0) {
#pragma unroll
      for (int p = 0; p < 2; ++p)
#pragma unroll
        for (int j = 0; j < 4; ++j) {
          const int row = (rt * 2 + p) * 16 + q * 4 + j;
          red[row * 8 + cg * 2]     = rs[p][j];
          red[row * 8 + cg * 2 + 1] = rss[p][j];
        }
    }
    __syncthreads();
    if (tid < 128) {
      float ms = 0.f, vs = 0.f;
#pragma unroll
      for (int ww = 0; ww < 4; ++ww) { ms += red[tid * 8 + ww * 2]; vs += red[tid * 8 + ww * 2 + 1]; }
      const float mm = ms * (1.f / 256.f);
      muinv[tid * 2]     = mm;
      muinv[tid * 2 + 1] = rsqrtf(vs * (1.f / 256.f) - mm * mm + 1e-5f);
    }
    __syncthreads();
#pragma unroll
    for (int p = 0; p < 2; ++p) {
#pragma unroll
      for (int j = 0; j < 4; ++j) {
        const int row = (rt * 2 + p) * 16 + q * 4 + j;
        const float mu = muinv[row * 2], inv = muinv[row * 2 + 1];
        const float wv = sw[(size_t)(n0 + row) * 16 + v];
#pragma unroll
        for (int u = 0; u < 4; ++u) {
          const float tv = (acc3[p][u][j] - mu) * inv * lgv[u] + lbv[u];
          outacc[p][u][j] += tv * wv;
        }
      }
    }
    __syncthreads();  // muinv reads done before next var reuses LDS
  }

#pragma unroll
  for (int p = 0; p < 2; ++p)
#pragma unroll
    for (int u = 0; u < 4; ++u) {
      const int col = cg * 64 + u * 16 + c;
#pragma unroll
      for (int j = 0; j < 4; ++j) {
        const int row = (rt * 2 + p) * 16 + q * 4 + j;
        atomicAdd(&out[(size_t)(n0 + row) * 256 + col], outacc[p][u][j]);
      }
    }
}

extern "C" void kernel_launch(void* const* d_in, const int* in_sizes, int n_in,
                              void* d_out, int out_size, void* d_ws, size_t ws_size,
                              hipStream_t stream) {
  const float* x     = (const float*)d_in[0];
  const float* ctx   = (const float*)d_in[1];
  const float* jWa   = (const float*)d_in[2];
  const float* jba   = (const float*)d_in[3];
  const float* jWc   = (const float*)d_in[4];
  const float* jWi   = (const float*)d_in[5];
  const float* jbi   = (const float*)d_in[6];
  const float* jWglu = (const float*)d_in[7];
  const float* jbglu = (const float*)d_in[8];
  const float* jWskip= (const float*)d_in[9];
  const float* jbskip= (const float*)d_in[10];
  const float* jlng  = (const float*)d_in[11];
  const float* jlnb  = (const float*)d_in[12];
  const float* vWa   = (const float*)d_in[13];
  const float* vba   = (const float*)d_in[14];
  const float* vWi   = (const float*)d_in[15];
  const float* vbi   = (const float*)d_in[16];
  const float* vWglu = (const float*)d_in[17];
  const float* vbglu = (const float*)d_in[18];
  const float* vlng  = (const float*)d_in[19];
  const float* vlnb  = (const float*)d_in[20];
  float* out = (float*)d_out;

  char* ws = (char*)d_ws;
  size_t off = 0;
  auto alloc = [&](size_t bytes) { void* p = ws + off; off += (bytes + 255) & ~(size_t)255; return p; };
  u16* bt1     = (u16*)alloc((size_t)272 * 4352 * 2);
  u16* wiT     = (u16*)alloc((size_t)256 * 256 * 2);
  u16* wgluT   = (u16*)alloc((size_t)32 * 256 * 2);
  u16* varw    = (u16*)alloc((size_t)16 * 262144 * 2);   // 16 vars x 16 tiles x 32KB
  u16* a_bf    = (u16*)alloc((size_t)8192 * 256 * 2);
  u16* i_bf    = (u16*)alloc((size_t)8192 * 256 * 2);
  float* skipf = (float*)alloc((size_t)8192 * 16 * 4);

  hipMemsetAsync(bt1, 0, (size_t)272 * 4352 * 2, stream);
  hipMemsetAsync(out, 0, (size_t)8192 * 256 * 4, stream);

  dim3 blk(256);
  transpose_cast<<<dim3(8, 128, 1),  blk, 0, stream>>>(jWa,   bt1,              4096, 256, 4352, 0, 0);
  transpose_cast<<<dim3(8, 8, 1),    blk, 0, stream>>>(jWc,   bt1 + 4096,       256,  256, 4352, 0, 0);
  transpose_cast<<<dim3(1, 128, 1),  blk, 0, stream>>>(jWskip,bt1 + 256 * 4352, 4096, 16,  4352, 0, 0);
  transpose_cast<<<dim3(8, 8, 1),    blk, 0, stream>>>(jWi,   wiT,   256, 256, 256, 0, 0);
  transpose_cast<<<dim3(1, 8, 1),    blk, 0, stream>>>(jWglu, wgluT, 256, 32,  256, 0, 0);
  var_w_prep<<<dim3(16, 4), blk, 0, stream>>>(vWa, varw, 0);
  var_w_prep<<<dim3(16, 4), blk, 0, stream>>>(vWi, varw, 4);
  var_wglu_prep<<<dim3(16, 8), blk, 0, stream>>>(vWglu, varw);

  gemm1<<<dim3(256), blk, 0, stream>>>(x, ctx, bt1, jba, jbskip, a_bf, skipf);
  gemm_i<<<dim3(256), blk, 0, stream>>>(a_bf, wiT, jbi, i_bf);
  joint_tail<<<dim3(2048), blk, 0, stream>>>(i_bf, wgluT, jbglu, skipf, jlng, jlnb,
                                             out + (size_t)8192 * 256);

  hipFuncSetAttribute((const void*)var_chain, hipFuncAttributeMaxDynamicSharedMemorySize, 136192);
  var_chain<<<dim3(4, 64), dim3(1024), 136192, stream>>>(x, varw, vba, vbi, vbglu,
                                                         vlng, vlnb,
                                                         out + (size_t)8192 * 256, out);
}

// Round 8
// 475.827 us; speedup vs baseline: 1.7069x; 1.0074x over previous
//
#include <hip/hip_runtime.h>

typedef unsigned short u16;
typedef __attribute__((ext_vector_type(8))) __bf16 bf16x8;
typedef __attribute__((ext_vector_type(4))) float f32x4;
typedef __attribute__((ext_vector_type(8))) u16 u16x8;

__device__ __forceinline__ u16 f2b(float f) {
  union { float f; unsigned u; } v; v.f = f;
  return (u16)((v.u + 0x7fffu + ((v.u >> 16) & 1u)) >> 16);
}
__device__ __forceinline__ float b2f(u16 h) {
  union { unsigned u; float f; } v; v.u = ((unsigned)h) << 16;
  return v.f;
}
__device__ __forceinline__ f32x4 mfma16(bf16x8 a, bf16x8 b, f32x4 c) {
  return __builtin_amdgcn_mfma_f32_16x16x32_bf16(a, b, c, 0, 0, 0);
}
__device__ __forceinline__ void gl_lds16(const void* g, void* l) {
  __builtin_amdgcn_global_load_lds(
      (const __attribute__((address_space(1))) void*)g,
      (__attribute__((address_space(3))) void*)l, 16, 0, 0);
}
__device__ __forceinline__ u16x8 cvt8(float4 a, float4 b) {
  u16x8 o;
  o[0] = f2b(a.x); o[1] = f2b(a.y); o[2] = f2b(a.z); o[3] = f2b(a.w);
  o[4] = f2b(b.x); o[5] = f2b(b.y); o[6] = f2b(b.z); o[7] = f2b(b.w);
  return o;
}

// ---------------- weight transpose+cast: src f32 [R,C] -> dst bf16 [C][R] (linear) ----------
__global__ __launch_bounds__(256) void transpose_cast(
    const float* __restrict__ src, u16* __restrict__ dst,
    int R, int C, int dstStride, long srcBatch, long dstBatch)
{
  __shared__ float tile[32][33];
  src += (long)blockIdx.z * srcBatch;
  dst += (long)blockIdx.z * dstBatch;
  const int c0 = blockIdx.x * 32, r0 = blockIdx.y * 32;
  const int tx = threadIdx.x & 31, ty = threadIdx.x >> 5;
  for (int i = ty; i < 32; i += 8) {
    int r = r0 + i, cc = c0 + tx;
    if (r < R && cc < C) tile[i][tx] = src[(long)r * C + cc];
  }
  __syncthreads();
  for (int i = ty; i < 32; i += 8) {
    int cc = c0 + i, r = r0 + tx;
    if (cc < C && r < R) dst[(long)cc * dstStride + r] = f2b(tile[tx][i]);
  }
}

// ---- var Wa/Wi -> pre-swizzled 32KB tiles: per (v,kc): [256 n][64 k2], chunk = n*8 + ((k2/8)^(n&7))
__global__ __launch_bounds__(256) void var_w_prep(
    const float* __restrict__ W, u16* __restrict__ dstbase, int rbase)
{
  const int v = blockIdx.x;   // 16
  const int kc = blockIdx.y;  // 4
  const int n = threadIdx.x;  // 256
  const float* src = W + (size_t)v * 65536 + (size_t)kc * 64 * 256 + n;
  u16* dst = dstbase + (size_t)v * 262144 + (size_t)(rbase + kc) * 16384;
#pragma unroll
  for (int l = 0; l < 8; ++l) {
    u16x8 o;
#pragma unroll
    for (int e = 0; e < 8; ++e) o[e] = f2b(src[(l * 8 + e) * 256]);
    const int chunk = n * 8 + (l ^ (n & 7));
    *(u16x8*)&dst[chunk * 8] = o;
  }
}

// ---- var Wglu -> tiles: per (v,kc): [512 n][32 k2], chunk = (n>>1)*8 + (((n&1)*4 + k2/8) ^ ((n>>1)&7))
__global__ __launch_bounds__(256) void var_wglu_prep(
    const float* __restrict__ W, u16* __restrict__ dstbase)
{
  const int v = blockIdx.x;   // 16
  const int kc = blockIdx.y;  // 8
  u16* dst = dstbase + (size_t)v * 262144 + (size_t)(8 + kc) * 16384;
#pragma unroll
  for (int half = 0; half < 2; ++half) {
    const int n = threadIdx.x + half * 256;
    const float* src = W + (size_t)v * 131072 + (size_t)kc * 32 * 512 + n;
    const int s = n >> 1;
#pragma unroll
    for (int l = 0; l < 4; ++l) {
      u16x8 o;
#pragma unroll
      for (int e = 0; e < 8; ++e) o[e] = f2b(src[(l * 8 + e) * 512]);
      const int chunk = s * 8 + ((((n & 1) * 4 + l)) ^ (s & 7));
      *(u16x8*)&dst[chunk * 8] = o;
    }
  }
}

// ---------------- gemm1 ----------------
#define K1TOT 4352
__global__ __launch_bounds__(256, 3) void gemm1(
    const float* __restrict__ x, const float* __restrict__ ctx,
    const u16* __restrict__ bt1, const float* __restrict__ ba,
    const float* __restrict__ bskip, u16* __restrict__ a_bf, float* __restrict__ skip_f)
{
  __shared__ u16 As[32 * 64];
  __shared__ u16 Bs[288 * 64];
  const int tid = threadIdx.x;
  const int n0 = blockIdx.x * 32;
  const int w = tid >> 6, lane = tid & 63;
  const int q = lane >> 4, c = lane & 15;
  const int rt = w & 1, cg = w >> 1;
  const int t0 = cg ? 9 : 0;
  const int nt = cg ? 8 : 9;

  f32x4 acc[9];
#pragma unroll
  for (int i = 0; i < 9; ++i) acc[i] = f32x4{0.f, 0.f, 0.f, 0.f};

  const int sr = tid >> 3, sp = tid & 7;
  const int sl = sp ^ (sr & 7);

  for (int kb = 0; kb < K1TOT; kb += 64) {
    {
      const float* s = (kb < 4096)
          ? (x + (size_t)(n0 + sr) * 4096 + kb + sl * 8)
          : (ctx + (size_t)(n0 + sr) * 256 + (kb - 4096) + sl * 8);
      float4 v0 = ((const float4*)s)[0];
      float4 v1 = ((const float4*)s)[1];
      *(u16x8*)&As[tid * 8] = cvt8(v0, v1);
    }
#pragma unroll
    for (int i = 0; i < 9; ++i) {
      const int cb = (i * 4 + w) * 64;
      const int cid = cb + lane;
      const int row = cid >> 3, p = cid & 7;
      const int l = p ^ (row & 7);
      const u16* src = (row < 272) ? (bt1 + (size_t)row * K1TOT + kb + l * 8) : bt1;
      gl_lds16(src, &Bs[cb * 8]);
    }
    __syncthreads();
#pragma unroll
    for (int kk = 0; kk < 2; ++kk) {
      const int arow = rt * 16 + c;
      bf16x8 af = *(const bf16x8*)&As[(arow * 64 + kk * 32 + q * 8) ^ ((arow & 7) << 3)];
#pragma unroll
      for (int ti = 0; ti < 9; ++ti) {
        if (ti < nt) {
          const int n16 = (t0 + ti) * 16 + c;
          bf16x8 bfr = *(const bf16x8*)&Bs[(n16 * 64 + kk * 32 + q * 8) ^ ((n16 & 7) << 3)];
          acc[ti] = mfma16(af, bfr, acc[ti]);
        }
      }
    }
    __syncthreads();
  }
#pragma unroll
  for (int ti = 0; ti < 9; ++ti) {
    if (ti < nt) {
      const int col = (t0 + ti) * 16 + c;
#pragma unroll
      for (int j = 0; j < 4; ++j) {
        const long n = n0 + rt * 16 + q * 4 + j;
        float vv = acc[ti][j];
        if (col < 256) {
          vv += ba[col];
          vv = vv > 0.f ? vv : expm1f(vv);
          a_bf[n * 256 + col] = f2b(vv);
        } else {
          skip_f[n * 16 + (col - 256)] = vv + bskip[col - 256];
        }
      }
    }
  }
}

// ---------------- gemm_i ----------------
__global__ __launch_bounds__(256, 3) void gemm_i(
    const u16* __restrict__ a_bf, const u16* __restrict__ wiT,
    const float* __restrict__ bi, u16* __restrict__ i_bf)
{
  __shared__ u16 As[32 * 64];
  __shared__ u16 Bs[256 * 64];
  const int tid = threadIdx.x;
  const int n0 = blockIdx.x * 32;
  const int w = tid >> 6, lane = tid & 63;
  const int q = lane >> 4, c = lane & 15;
  const int rt = w & 1, cg = w >> 1;

  f32x4 acc[8];
#pragma unroll
  for (int i = 0; i < 8; ++i) acc[i] = f32x4{0.f, 0.f, 0.f, 0.f};

  for (int kb = 0; kb < 256; kb += 64) {
    {
      const int row = tid >> 3, p = tid & 7;
      const int l = p ^ (row & 7);
      gl_lds16(a_bf + (size_t)(n0 + row) * 256 + kb + l * 8, &As[w * 512]);
    }
#pragma unroll
    for (int i = 0; i < 8; ++i) {
      const int cb = (i * 4 + w) * 64;
      const int cid = cb + lane;
      const int row = cid >> 3, p = cid & 7;
      const int l = p ^ (row & 7);
      gl_lds16(wiT + (size_t)row * 256 + kb + l * 8, &Bs[cb * 8]);
    }
    __syncthreads();
#pragma unroll
    for (int kk = 0; kk < 2; ++kk) {
      const int arow = rt * 16 + c;
      bf16x8 af = *(const bf16x8*)&As[(arow * 64 + kk * 32 + q * 8) ^ ((arow & 7) << 3)];
#pragma unroll
      for (int ti = 0; ti < 8; ++ti) {
        const int n16 = (cg * 8 + ti) * 16 + c;
        bf16x8 bfr = *(const bf16x8*)&Bs[(n16 * 64 + kk * 32 + q * 8) ^ ((n16 & 7) << 3)];
        acc[ti] = mfma16(af, bfr, acc[ti]);
      }
    }
    __syncthreads();
  }
#pragma unroll
  for (int ti = 0; ti < 8; ++ti) {
    const int col = (cg * 8 + ti) * 16 + c;
    const float bb = bi[col];
#pragma unroll
    for (int j = 0; j < 4; ++j) {
      const long n = n0 + rt * 16 + q * 4 + j;
      i_bf[n * 256 + col] = f2b(acc[ti][j] + bb);
    }
  }
}

// ---------------- joint tail ----------------
__global__ __launch_bounds__(256) void joint_tail(
    const u16* __restrict__ i_bf, const u16* __restrict__ wgluT,
    const float* __restrict__ bglu, const float* __restrict__ skip_f,
    const float* __restrict__ lng, const float* __restrict__ lnb,
    float* __restrict__ swout)
{
  __shared__ float wlds[32 * 257];
  __shared__ float ilds[4][256];
  const int tid = threadIdx.x;
  for (int jj = 0; jj < 32; ++jj) wlds[jj * 257 + tid] = b2f(wgluT[jj * 256 + tid]);
  const int w = tid >> 6, lane = tid & 63;
  const long n = (long)blockIdx.x * 4 + w;
  {
    const u16* src = i_bf + n * 256 + lane * 4;
    float4 f;
    f.x = b2f(src[0]); f.y = b2f(src[1]); f.z = b2f(src[2]); f.w = b2f(src[3]);
    *(float4*)&ilds[w][lane * 4] = f;
  }
  __syncthreads();
  const int cc32 = lane & 31;
  const int k0 = (lane >> 5) * 128;
  float acc = 0.f;
  for (int k = 0; k < 128; ++k) acc += ilds[w][k0 + k] * wlds[cc32 * 257 + k0 + k];
  acc += __shfl_xor(acc, 32, 64);
  const float gfull = acc + bglu[cc32];
  const int cc = lane & 15;
  const float g1 = __shfl(gfull, cc, 64);
  const float g2 = __shfl(gfull, cc + 16, 64);
  const float glu = g1 / (1.f + __expf(-g2));
  const float y = glu + skip_f[n * 16 + cc];
  float s = y, ss = y * y;
#pragma unroll
  for (int d = 1; d < 16; d <<= 1) { s += __shfl_xor(s, d, 64); ss += __shfl_xor(ss, d, 64); }
  const float m = s * (1.f / 16.f);
  const float var = ss * (1.f / 16.f) - m * m;
  const float t = (y - m) * rsqrtf(var + 1e-5f) * lng[cc] + lnb[cc];
  float mx = t;
#pragma unroll
  for (int d = 1; d < 16; d <<= 1) mx = fmaxf(mx, __shfl_xor(mx, d, 64));
  const float e = __expf(t - mx);
  float es = e;
#pragma unroll
  for (int d = 1; d < 16; d <<= 1) es += __shfl_xor(es, d, 64);
  if (lane < 16) swout[n * 16 + lane] = e / es;
}

// ---------------- per-variable fused chain v4: counted-vmcnt pipeline ----------------
// M=128, 1024 threads (16 waves), 4 vars/block, grid (4,64): one var-group per XCD.
// Tile round: compute(buf[t&1]) -> s_barrier(B1) -> STAGE(buf[t&1], t+2)
//  -> s_waitcnt vmcnt(2) [stage(t+1) landed; only stage(t+2) in flight] -> s_barrier(B2).
// vmcnt is per-wave oldest-first; STAGE = 2 loads/wave. Writebacks/epilogue use plain
// __syncthreads (full drain, race-free).
__global__ __launch_bounds__(1024, 1) void var_chain(
    const float* __restrict__ x, const u16* __restrict__ varw,
    const float* __restrict__ vba, const float* __restrict__ vbi,
    const float* __restrict__ vbglu, const float* __restrict__ vlng,
    const float* __restrict__ vlnb, const float* __restrict__ sw,
    float* __restrict__ out)
{
  extern __shared__ u16 smem[];
  u16* const xt1 = smem;                        // 32768 u16 (64KB): x -> av -> iv in place
  u16* const wtb = smem + 32768;                // 2 x 16384 u16 (2 x 32KB) weight dbuf
  float* const red   = (float*)(smem + 65536);  // [128][4][2] floats (4KB)
  float* const muinv = red + 1024;              // [128][2] floats (1KB)

  const int tid = threadIdx.x;
  const int w = tid >> 6, lane = tid & 63;
  const int q = lane >> 4, c = lane & 15;
  const int rt = w >> 2, cg = w & 3;
  const int vbase = blockIdx.x * 4;
  const int n0 = blockIdx.y * 128;

  f32x4 outacc[2][4];
#pragma unroll
  for (int p = 0; p < 2; ++p)
#pragma unroll
    for (int u = 0; u < 4; ++u) outacc[p][u] = f32x4{0.f, 0.f, 0.f, 0.f};

  auto STAGE = [&](int b, int tn) {  // stage 32KB tile tn into wtb[b]; 2 loads/wave
    const u16* tb = varw + (size_t)(vbase + (tn >> 4)) * 262144 + (size_t)(tn & 15) * 16384;
    u16* dst = wtb + (b << 14);
#pragma unroll
    for (int i = 0; i < 2; ++i) {
      const int cb = (i * 16 + w) * 64;
      gl_lds16(tb + (size_t)(cb + lane) * 8, dst + (size_t)cb * 8);
    }
  };
  auto XSTAGE = [&](int v) {  // xt1 = x tile (linear chunks; source columns pre-permuted)
#pragma unroll
    for (int jj = 0; jj < 4; ++jj) {
      const int cid = jj * 1024 + tid;
      const int r = cid >> 5, p = cid & 31;
      const int l = (p & 24) | ((p & 7) ^ (r & 7));
      const float* s = x + (size_t)(n0 + r) * 4096 + (size_t)v * 256 + l * 8;
      float4 v0 = ((const float4*)s)[0];
      float4 v1 = ((const float4*)s)[1];
      *(u16x8*)&xt1[cid * 8] = cvt8(v0, v1);
    }
  };

  auto ROUND_TAIL = [&](int t) {
    __builtin_amdgcn_s_barrier();                    // B1: reads of buf done block-wide
    __builtin_amdgcn_sched_barrier(0);
    STAGE(t & 1, (t + 2 < 64) ? t + 2 : 63);
    __builtin_amdgcn_sched_barrier(0);
    asm volatile("s_waitcnt vmcnt(2)" ::: "memory"); // stage(t+1) resident (per-wave)
    __builtin_amdgcn_sched_barrier(0);
    __builtin_amdgcn_s_barrier();                    // B2: block-wide
    __builtin_amdgcn_sched_barrier(0);
  };

  // prologue: tiles 0,1 in flight; x tile for var 0; one full drain
  STAGE(0, 0);
  STAGE(1, 1);
  XSTAGE(vbase);
  __syncthreads();

  int t = 0;  // global tile counter 0..63 (16 per var)
  for (int vi = 0; vi < 4; ++vi) {
    const int v = vbase + vi;

    f32x4 acc2[2][4];
#pragma unroll
    for (int p = 0; p < 2; ++p)
#pragma unroll
      for (int ti = 0; ti < 4; ++ti) acc2[p][ti] = f32x4{0.f, 0.f, 0.f, 0.f};

    // ---- m1: av = elu(x @ WaT + ba), 4 rounds ----
    for (int kc = 0; kc < 4; ++kc, ++t) {
      const u16* wcur = wtb + ((t & 1) << 14);
      __builtin_amdgcn_s_setprio(1);
#pragma unroll
      for (int kk = 0; kk < 2; ++kk) {
        bf16x8 a[2];
#pragma unroll
        for (int p = 0; p < 2; ++p) {
          const int r = (rt * 2 + p) * 16 + c;
          a[p] = *(const bf16x8*)&xt1[(r * 256 + kc * 64 + kk * 32 + q * 8) ^ ((r & 7) << 3)];
        }
#pragma unroll
        for (int ti = 0; ti < 4; ++ti) {
          const int n16 = (cg * 4 + ti) * 16 + c;
          bf16x8 b = *(const bf16x8*)&wcur[(n16 * 64 + kk * 32 + q * 8) ^ ((n16 & 7) << 3)];
          acc2[0][ti] = mfma16(a[0], b, acc2[0][ti]);
          acc2[1][ti] = mfma16(a[1], b, acc2[1][ti]);
        }
      }
      __builtin_amdgcn_s_setprio(0);
      ROUND_TAIL(t);
    }
    // write av into xt1 (full drain keeps the writeback race-free)
#pragma unroll
    for (int p = 0; p < 2; ++p)
#pragma unroll
      for (int ti = 0; ti < 4; ++ti) {
        const int col = (cg * 4 + ti) * 16 + c;
        const float bb = vba[v * 256 + col];
#pragma unroll
        for (int j = 0; j < 4; ++j) {
          const int row = (rt * 2 + p) * 16 + q * 4 + j;
          float vv = acc2[p][ti][j] + bb;
          vv = vv > 0.f ? vv : expm1f(vv);
          xt1[(row * 256 + col) ^ ((row & 7) << 3)] = f2b(vv);
        }
      }
    __syncthreads();

    // ---- m2: iv = av @ WiT + bi, 4 rounds ----
#pragma unroll
    for (int p = 0; p < 2; ++p)
#pragma unroll
      for (int ti = 0; ti < 4; ++ti) acc2[p][ti] = f32x4{0.f, 0.f, 0.f, 0.f};
    for (int kc = 0; kc < 4; ++kc, ++t) {
      const u16* wcur = wtb + ((t & 1) << 14);
      __builtin_amdgcn_s_setprio(1);
#pragma unroll
      for (int kk = 0; kk < 2; ++kk) {
        bf16x8 a[2];
#pragma unroll
        for (int p = 0; p < 2; ++p) {
          const int r = (rt * 2 + p) * 16 + c;
          a[p] = *(const bf16x8*)&xt1[(r * 256 + kc * 64 + kk * 32 + q * 8) ^ ((r & 7) << 3)];
        }
#pragma unroll
        for (int ti = 0; ti < 4; ++ti) {
          const int n16 = (cg * 4 + ti) * 16 + c;
          bf16x8 b = *(const bf16x8*)&wcur[(n16 * 64 + kk * 32 + q * 8) ^ ((n16 & 7) << 3)];
          acc2[0][ti] = mfma16(a[0], b, acc2[0][ti]);
          acc2[1][ti] = mfma16(a[1], b, acc2[1][ti]);
        }
      }
      __builtin_amdgcn_s_setprio(0);
      ROUND_TAIL(t);
    }
    // write iv into xt1
#pragma unroll
    for (int p = 0; p < 2; ++p)
#pragma unroll
      for (int ti = 0; ti < 4; ++ti) {
        const int col = (cg * 4 + ti) * 16 + c;
        const float bb = vbi[v * 256 + col];
#pragma unroll
        for (int j = 0; j < 4; ++j) {
          const int row = (rt * 2 + p) * 16 + q * 4 + j;
          xt1[(row * 256 + col) ^ ((row & 7) << 3)] = f2b(acc2[p][ti][j] + bb);
        }
      }
    __syncthreads();

    // ---- m3: gv = iv @ WgluT (N=512), 8 rounds ----
    f32x4 acc3[2][8];
#pragma unroll
    for (int p = 0; p < 2; ++p)
#pragma unroll
      for (int u = 0; u < 8; ++u) acc3[p][u] = f32x4{0.f, 0.f, 0.f, 0.f};
    for (int kc = 0; kc < 8; ++kc, ++t) {
      const u16* wcur = wtb + ((t & 1) << 14);
      bf16x8 a[2];
#pragma unroll
      for (int p = 0; p < 2; ++p) {
        const int r = (rt * 2 + p) * 16 + c;
        a[p] = *(const bf16x8*)&xt1[(r * 256 + kc * 32 + q * 8) ^ ((r & 7) << 3)];
      }
      __builtin_amdgcn_s_setprio(1);
#pragma unroll
      for (int u = 0; u < 8; ++u) {
        const int ct = cg * 4 + (u & 3) + ((u >> 2) << 4);
        const int n = ct * 16 + c;
        const int idx = (n >> 1) * 64 + ((((n & 1) * 4 + q) ^ ((n >> 1) & 7)) * 8);
        bf16x8 b = *(const bf16x8*)&wcur[idx];
        acc3[0][u] = mfma16(a[0], b, acc3[0][u]);
        acc3[1][u] = mfma16(a[1], b, acc3[1][u]);
      }
      __builtin_amdgcn_s_setprio(0);
      ROUND_TAIL(t);
    }

    // ---- epilogue: GLU + residual (global) + LN + weighted accumulate ----
    float b1v[4], b2v[4], lgv[4], lbv[4];
#pragma unroll
    for (int u = 0; u < 4; ++u) {
      const int col = cg * 64 + u * 16 + c;
      b1v[u] = vbglu[v * 512 + col];
      b2v[u] = vbglu[v * 512 + 256 + col];
      lgv[u] = vlng[v * 256 + col];
      lbv[u] = vlnb[v * 256 + col];
    }
    float rs[2][4], rss[2][4];
#pragma unroll
    for (int p = 0; p < 2; ++p)
#pragma unroll
      for (int j = 0; j < 4; ++j) { rs[p][j] = 0.f; rss[p][j] = 0.f; }
#pragma unroll
    for (int p = 0; p < 2; ++p)
#pragma unroll
      for (int u = 0; u < 4; ++u) {
        const int col = cg * 64 + u * 16 + c;
#pragma unroll
        for (int j = 0; j < 4; ++j) {
          const int row = (rt * 2 + p) * 16 + q * 4 + j;
          const float g1 = acc3[p][u][j] + b1v[u];
          const float g2 = acc3[p][u + 4][j] + b2v[u];
          const float glu = g1 / (1.f + __expf(-g2));
          const float r = glu + x[(size_t)(n0 + row) * 4096 + (size_t)v * 256 + col];
          acc3[p][u][j] = r;
          rs[p][j] += r; rss[p][j] += r * r;
        }
      }
#pragma unroll
    for (int p = 0; p < 2; ++p)
#pragma unroll
      for (int j = 0; j < 4; ++j)
#pragma unroll
        for (int d = 1; d < 16; d <<= 1) {
          rs[p][j]  += __shfl_xor(rs[p][j], d, 64);
          rss[p][j] += __shfl_xor(rss[p][j], d, 64);
        }
    if (c == 0) {
#pragma unroll
      for (int p = 0; p < 2; ++p)
#pragma unroll
        for (int j = 0; j < 4; ++j) {
          const int row = (rt * 2 + p) * 16 + q * 4 + j;
          red[row * 8 + cg * 2]     = rs[p][j];
          red[row * 8 + cg * 2 + 1] = rss[p][j];
        }
    }
    __syncthreads();
    if (tid < 128) {
      float ms = 0.f, vs = 0.f;
#pragma unroll
      for (int ww = 0; ww < 4; ++ww) { ms += red[tid * 8 + ww * 2]; vs += red[tid * 8 + ww * 2 + 1]; }
      const float mm = ms * (1.f / 256.f);
      muinv[tid * 2]     = mm;
      muinv[tid * 2 + 1] = rsqrtf(vs * (1.f / 256.f) - mm * mm + 1e-5f);
    }
    __syncthreads();
#pragma unroll
    for (int p = 0; p < 2; ++p) {
#pragma unroll
      for (int j = 0; j < 4; ++j) {
        const int row = (rt * 2 + p) * 16 + q * 4 + j;
        const float mu = muinv[row * 2], inv = muinv[row * 2 + 1];
        const float wv = sw[(size_t)(n0 + row) * 16 + v];
#pragma unroll
        for (int u = 0; u < 4; ++u) {
          const float tv = (acc3[p][u][j] - mu) * inv * lgv[u] + lbv[u];
          outacc[p][u][j] += tv * wv;
        }
      }
    }
    __syncthreads();  // muinv/red reads done before next var reuses LDS
    if (vi < 3) {
      XSTAGE(v + 1);
      __syncthreads();  // xt1(x) visible; pipeline tiles stay resident
    }
  }

#pragma unroll
  for (int p = 0; p < 2; ++p)
#pragma unroll
    for (int u = 0; u < 4; ++u) {
      const int col = cg * 64 + u * 16 + c;
#pragma unroll
      for (int j = 0; j < 4; ++j) {
        const int row = (rt * 2 + p) * 16 + q * 4 + j;
        atomicAdd(&out[(size_t)(n0 + row) * 256 + col], outacc[p][u][j]);
      }
    }
}

extern "C" void kernel_launch(void* const* d_in, const int* in_sizes, int n_in,
                              void* d_out, int out_size, void* d_ws, size_t ws_size,
                              hipStream_t stream) {
  const float* x     = (const float*)d_in[0];
  const float* ctx   = (const float*)d_in[1];
  const float* jWa   = (const float*)d_in[2];
  const float* jba   = (const float*)d_in[3];
  const float* jWc   = (const float*)d_in[4];
  const float* jWi   = (const float*)d_in[5];
  const float* jbi   = (const float*)d_in[6];
  const float* jWglu = (const float*)d_in[7];
  const float* jbglu = (const float*)d_in[8];
  const float* jWskip= (const float*)d_in[9];
  const float* jbskip= (const float*)d_in[10];
  const float* jlng  = (const float*)d_in[11];
  const float* jlnb  = (const float*)d_in[12];
  const float* vWa   = (const float*)d_in[13];
  const float* vba   = (const float*)d_in[14];
  const float* vWi   = (const float*)d_in[15];
  const float* vbi   = (const float*)d_in[16];
  const float* vWglu = (const float*)d_in[17];
  const float* vbglu = (const float*)d_in[18];
  const float* vlng  = (const float*)d_in[19];
  const float* vlnb  = (const float*)d_in[20];
  float* out = (float*)d_out;

  char* ws = (char*)d_ws;
  size_t off = 0;
  auto alloc = [&](size_t bytes) { void* p = ws + off; off += (bytes + 255) & ~(size_t)255; return p; };
  u16* bt1     = (u16*)alloc((size_t)272 * 4352 * 2);
  u16* wiT     = (u16*)alloc((size_t)256 * 256 * 2);
  u16* wgluT   = (u16*)alloc((size_t)32 * 256 * 2);
  u16* varw    = (u16*)alloc((size_t)16 * 262144 * 2);   // 16 vars x 16 tiles x 32KB
  u16* a_bf    = (u16*)alloc((size_t)8192 * 256 * 2);
  u16* i_bf    = (u16*)alloc((size_t)8192 * 256 * 2);
  float* skipf = (float*)alloc((size_t)8192 * 16 * 4);

  hipMemsetAsync(bt1, 0, (size_t)272 * 4352 * 2, stream);
  hipMemsetAsync(out, 0, (size_t)8192 * 256 * 4, stream);

  dim3 blk(256);
  transpose_cast<<<dim3(8, 128, 1),  blk, 0, stream>>>(jWa,   bt1,              4096, 256, 4352, 0, 0);
  transpose_cast<<<dim3(8, 8, 1),    blk, 0, stream>>>(jWc,   bt1 + 4096,       256,  256, 4352, 0, 0);
  transpose_cast<<<dim3(1, 128, 1),  blk, 0, stream>>>(jWskip,bt1 + 256 * 4352, 4096, 16,  4352, 0, 0);
  transpose_cast<<<dim3(8, 8, 1),    blk, 0, stream>>>(jWi,   wiT,   256, 256, 256, 0, 0);
  transpose_cast<<<dim3(1, 8, 1),    blk, 0, stream>>>(jWglu, wgluT, 256, 32,  256, 0, 0);
  var_w_prep<<<dim3(16, 4), blk, 0, stream>>>(vWa, varw, 0);
  var_w_prep<<<dim3(16, 4), blk, 0, stream>>>(vWi, varw, 4);
  var_wglu_prep<<<dim3(16, 8), blk, 0, stream>>>(vWglu, varw);

  gemm1<<<dim3(256), blk, 0, stream>>>(x, ctx, bt1, jba, jbskip, a_bf, skipf);
  gemm_i<<<dim3(256), blk, 0, stream>>>(a_bf, wiT, jbi, i_bf);
  joint_tail<<<dim3(2048), blk, 0, stream>>>(i_bf, wgluT, jbglu, skipf, jlng, jlnb,
                                             out + (size_t)8192 * 256);

  hipFuncSetAttribute((const void*)var_chain, hipFuncAttributeMaxDynamicSharedMemorySize, 136192);
  var_chain<<<dim3(4, 64), dim3(1024), 136192, stream>>>(x, varw, vba, vbi, vbglu,
                                                         vlng, vlnb,
                                                         out + (size_t)8192 * 256, out);
}

// Round 10
// 470.136 us; speedup vs baseline: 1.7275x; 1.0121x over previous
//
#include <hip/hip_runtime.h>

typedef unsigned short u16;
typedef __attribute__((ext_vector_type(8))) __bf16 bf16x8;
typedef __attribute__((ext_vector_type(4))) float f32x4;
typedef __attribute__((ext_vector_type(8))) u16 u16x8;

__device__ __forceinline__ u16 f2b(float f) {
  union { float f; unsigned u; } v; v.f = f;
  return (u16)((v.u + 0x7fffu + ((v.u >> 16) & 1u)) >> 16);
}
__device__ __forceinline__ float b2f(u16 h) {
  union { unsigned u; float f; } v; v.u = ((unsigned)h) << 16;
  return v.f;
}
__device__ __forceinline__ f32x4 mfma16(bf16x8 a, bf16x8 b, f32x4 c) {
  return __builtin_amdgcn_mfma_f32_16x16x32_bf16(a, b, c, 0, 0, 0);
}
__device__ __forceinline__ void gl_lds16(const void* g, void* l) {
  __builtin_amdgcn_global_load_lds(
      (const __attribute__((address_space(1))) void*)g,
      (__attribute__((address_space(3))) void*)l, 16, 0, 0);
}
__device__ __forceinline__ u16x8 cvt8(float4 a, float4 b) {
  u16x8 o;
  o[0] = f2b(a.x); o[1] = f2b(a.y); o[2] = f2b(a.z); o[3] = f2b(a.w);
  o[4] = f2b(b.x); o[5] = f2b(b.y); o[6] = f2b(b.z); o[7] = f2b(b.w);
  return o;
}
__device__ __forceinline__ u16x8 cvt8v(f32x4 a, f32x4 b) {
  u16x8 o;
  o[0] = f2b(a[0]); o[1] = f2b(a[1]); o[2] = f2b(a[2]); o[3] = f2b(a[3]);
  o[4] = f2b(b[0]); o[5] = f2b(b[1]); o[6] = f2b(b[2]); o[7] = f2b(b[3]);
  return o;
}

// ---------------- weight transpose+cast: src f32 [R,C] -> dst bf16 [C][R] (linear) ----------
__global__ __launch_bounds__(256) void transpose_cast(
    const float* __restrict__ src, u16* __restrict__ dst,
    int R, int C, int dstStride, long srcBatch, long dstBatch)
{
  __shared__ float tile[32][33];
  src += (long)blockIdx.z * srcBatch;
  dst += (long)blockIdx.z * dstBatch;
  const int c0 = blockIdx.x * 32, r0 = blockIdx.y * 32;
  const int tx = threadIdx.x & 31, ty = threadIdx.x >> 5;
  for (int i = ty; i < 32; i += 8) {
    int r = r0 + i, cc = c0 + tx;
    if (r < R && cc < C) tile[i][tx] = src[(long)r * C + cc];
  }
  __syncthreads();
  for (int i = ty; i < 32; i += 8) {
    int cc = c0 + i, r = r0 + tx;
    if (cc < C && r < R) dst[(long)cc * dstStride + r] = f2b(tile[tx][i]);
  }
}

// ---- var Wa/Wi -> pre-swizzled 32KB tiles: per (v,kc): [256 n][64 k2], chunk = n*8 + ((k2/8)^(n&7))
__global__ __launch_bounds__(256) void var_w_prep(
    const float* __restrict__ W, u16* __restrict__ dstbase, int rbase)
{
  const int v = blockIdx.x;   // 16
  const int kc = blockIdx.y;  // 4
  const int n = threadIdx.x;  // 256
  const float* src = W + (size_t)v * 65536 + (size_t)kc * 64 * 256 + n;
  u16* dst = dstbase + (size_t)v * 262144 + (size_t)(rbase + kc) * 16384;
#pragma unroll
  for (int l = 0; l < 8; ++l) {
    u16x8 o;
#pragma unroll
    for (int e = 0; e < 8; ++e) o[e] = f2b(src[(l * 8 + e) * 256]);
    const int chunk = n * 8 + (l ^ (n & 7));
    *(u16x8*)&dst[chunk * 8] = o;
  }
}

// ---- var Wglu -> tiles: per (v,kc): [512 n][32 k2], chunk = (n>>1)*8 + (((n&1)*4 + k2/8) ^ ((n>>1)&7))
__global__ __launch_bounds__(256) void var_wglu_prep(
    const float* __restrict__ W, u16* __restrict__ dstbase)
{
  const int v = blockIdx.x;   // 16
  const int kc = blockIdx.y;  // 8
  u16* dst = dstbase + (size_t)v * 262144 + (size_t)(8 + kc) * 16384;
#pragma unroll
  for (int half = 0; half < 2; ++half) {
    const int n = threadIdx.x + half * 256;
    const float* src = W + (size_t)v * 131072 + (size_t)kc * 32 * 512 + n;
    const int s = n >> 1;
#pragma unroll
    for (int l = 0; l < 4; ++l) {
      u16x8 o;
#pragma unroll
      for (int e = 0; e < 8; ++e) o[e] = f2b(src[(l * 8 + e) * 512]);
      const int chunk = s * 8 + ((((n & 1) * 4 + l)) ^ (s & 7));
      *(u16x8*)&dst[chunk * 8] = o;
    }
  }
}

// ---------------- gemm1 ----------------
#define K1TOT 4352
__global__ __launch_bounds__(256, 3) void gemm1(
    const float* __restrict__ x, const float* __restrict__ ctx,
    const u16* __restrict__ bt1, const float* __restrict__ ba,
    const float* __restrict__ bskip, u16* __restrict__ a_bf, float* __restrict__ skip_f)
{
  __shared__ u16 As[32 * 64];
  __shared__ u16 Bs[288 * 64];
  const int tid = threadIdx.x;
  const int n0 = blockIdx.x * 32;
  const int w = tid >> 6, lane = tid & 63;
  const int q = lane >> 4, c = lane & 15;
  const int rt = w & 1, cg = w >> 1;
  const int t0 = cg ? 9 : 0;
  const int nt = cg ? 8 : 9;

  f32x4 acc[9];
#pragma unroll
  for (int i = 0; i < 9; ++i) acc[i] = f32x4{0.f, 0.f, 0.f, 0.f};

  const int sr = tid >> 3, sp = tid & 7;
  const int sl = sp ^ (sr & 7);

  for (int kb = 0; kb < K1TOT; kb += 64) {
    {
      const float* s = (kb < 4096)
          ? (x + (size_t)(n0 + sr) * 4096 + kb + sl * 8)
          : (ctx + (size_t)(n0 + sr) * 256 + (kb - 4096) + sl * 8);
      float4 v0 = ((const float4*)s)[0];
      float4 v1 = ((const float4*)s)[1];
      *(u16x8*)&As[tid * 8] = cvt8(v0, v1);
    }
#pragma unroll
    for (int i = 0; i < 9; ++i) {
      const int cb = (i * 4 + w) * 64;
      const int cid = cb + lane;
      const int row = cid >> 3, p = cid & 7;
      const int l = p ^ (row & 7);
      const u16* src = (row < 272) ? (bt1 + (size_t)row * K1TOT + kb + l * 8) : bt1;
      gl_lds16(src, &Bs[cb * 8]);
    }
    __syncthreads();
#pragma unroll
    for (int kk = 0; kk < 2; ++kk) {
      const int arow = rt * 16 + c;
      bf16x8 af = *(const bf16x8*)&As[(arow * 64 + kk * 32 + q * 8) ^ ((arow & 7) << 3)];
#pragma unroll
      for (int ti = 0; ti < 9; ++ti) {
        if (ti < nt) {
          const int n16 = (t0 + ti) * 16 + c;
          bf16x8 bfr = *(const bf16x8*)&Bs[(n16 * 64 + kk * 32 + q * 8) ^ ((n16 & 7) << 3)];
          acc[ti] = mfma16(af, bfr, acc[ti]);
        }
      }
    }
    __syncthreads();
  }
#pragma unroll
  for (int ti = 0; ti < 9; ++ti) {
    if (ti < nt) {
      const int col = (t0 + ti) * 16 + c;
#pragma unroll
      for (int j = 0; j < 4; ++j) {
        const long n = n0 + rt * 16 + q * 4 + j;
        float vv = acc[ti][j];
        if (col < 256) {
          vv += ba[col];
          vv = vv > 0.f ? vv : expm1f(vv);
          a_bf[n * 256 + col] = f2b(vv);
        } else {
          skip_f[n * 16 + (col - 256)] = vv + bskip[col - 256];
        }
      }
    }
  }
}

// ---------------- gemm_i ----------------
__global__ __launch_bounds__(256, 3) void gemm_i(
    const u16* __restrict__ a_bf, const u16* __restrict__ wiT,
    const float* __restrict__ bi, u16* __restrict__ i_bf)
{
  __shared__ u16 As[32 * 64];
  __shared__ u16 Bs[256 * 64];
  const int tid = threadIdx.x;
  const int n0 = blockIdx.x * 32;
  const int w = tid >> 6, lane = tid & 63;
  const int q = lane >> 4, c = lane & 15;
  const int rt = w & 1, cg = w >> 1;

  f32x4 acc[8];
#pragma unroll
  for (int i = 0; i < 8; ++i) acc[i] = f32x4{0.f, 0.f, 0.f, 0.f};

  for (int kb = 0; kb < 256; kb += 64) {
    {
      const int row = tid >> 3, p = tid & 7;
      const int l = p ^ (row & 7);
      gl_lds16(a_bf + (size_t)(n0 + row) * 256 + kb + l * 8, &As[w * 512]);
    }
#pragma unroll
    for (int i = 0; i < 8; ++i) {
      const int cb = (i * 4 + w) * 64;
      const int cid = cb + lane;
      const int row = cid >> 3, p = cid & 7;
      const int l = p ^ (row & 7);
      gl_lds16(wiT + (size_t)row * 256 + kb + l * 8, &Bs[cb * 8]);
    }
    __syncthreads();
#pragma unroll
    for (int kk = 0; kk < 2; ++kk) {
      const int arow = rt * 16 + c;
      bf16x8 af = *(const bf16x8*)&As[(arow * 64 + kk * 32 + q * 8) ^ ((arow & 7) << 3)];
#pragma unroll
      for (int ti = 0; ti < 8; ++ti) {
        const int n16 = (cg * 8 + ti) * 16 + c;
        bf16x8 bfr = *(const bf16x8*)&Bs[(n16 * 64 + kk * 32 + q * 8) ^ ((n16 & 7) << 3)];
        acc[ti] = mfma16(af, bfr, acc[ti]);
      }
    }
    __syncthreads();
  }
#pragma unroll
  for (int ti = 0; ti < 8; ++ti) {
    const int col = (cg * 8 + ti) * 16 + c;
    const float bb = bi[col];
#pragma unroll
    for (int j = 0; j < 4; ++j) {
      const long n = n0 + rt * 16 + q * 4 + j;
      i_bf[n * 256 + col] = f2b(acc[ti][j] + bb);
    }
  }
}

// ---------------- joint tail ----------------
__global__ __launch_bounds__(256) void joint_tail(
    const u16* __restrict__ i_bf, const u16* __restrict__ wgluT,
    const float* __restrict__ bglu, const float* __restrict__ skip_f,
    const float* __restrict__ lng, const float* __restrict__ lnb,
    float* __restrict__ swout)
{
  __shared__ float wlds[32 * 257];
  __shared__ float ilds[4][256];
  const int tid = threadIdx.x;
  for (int jj = 0; jj < 32; ++jj) wlds[jj * 257 + tid] = b2f(wgluT[jj * 256 + tid]);
  const int w = tid >> 6, lane = tid & 63;
  const long n = (long)blockIdx.x * 4 + w;
  {
    const u16* src = i_bf + n * 256 + lane * 4;
    float4 f;
    f.x = b2f(src[0]); f.y = b2f(src[1]); f.z = b2f(src[2]); f.w = b2f(src[3]);
    *(float4*)&ilds[w][lane * 4] = f;
  }
  __syncthreads();
  const int cc32 = lane & 31;
  const int k0 = (lane >> 5) * 128;
  float acc = 0.f;
  for (int k = 0; k < 128; ++k) acc += ilds[w][k0 + k] * wlds[cc32 * 257 + k0 + k];
  acc += __shfl_xor(acc, 32, 64);
  const float gfull = acc + bglu[cc32];
  const int cc = lane & 15;
  const float g1 = __shfl(gfull, cc, 64);
  const float g2 = __shfl(gfull, cc + 16, 64);
  const float glu = g1 / (1.f + __expf(-g2));
  const float y = glu + skip_f[n * 16 + cc];
  float s = y, ss = y * y;
#pragma unroll
  for (int d = 1; d < 16; d <<= 1) { s += __shfl_xor(s, d, 64); ss += __shfl_xor(ss, d, 64); }
  const float m = s * (1.f / 16.f);
  const float var = ss * (1.f / 16.f) - m * m;
  const float t = (y - m) * rsqrtf(var + 1e-5f) * lng[cc] + lnb[cc];
  float mx = t;
#pragma unroll
  for (int d = 1; d < 16; d <<= 1) mx = fmaxf(mx, __shfl_xor(mx, d, 64));
  const float e = __expf(t - mx);
  float es = e;
#pragma unroll
  for (int d = 1; d < 16; d <<= 1) es += __shfl_xor(es, d, 64);
  if (lane < 16) swout[n * 16 + lane] = e / es;
}

// ---------------- reduce over 4 var-group partials ----------------
__global__ __launch_bounds__(256) void reduce4(
    const float* __restrict__ part, float* __restrict__ out)
{
  const size_t i = ((size_t)blockIdx.x * 256 + threadIdx.x) * 4;
  float4 a = *(const float4*)(part + i);
  float4 b = *(const float4*)(part + i + 2097152);
  float4 c = *(const float4*)(part + i + 4194304);
  float4 d = *(const float4*)(part + i + 6291456);
  float4 o;
  o.x = a.x + b.x + c.x + d.x;
  o.y = a.y + b.y + c.y + d.y;
  o.z = a.z + b.z + c.z + d.z;
  o.w = a.w + b.w + c.w + d.w;
  *(float4*)(out + i) = o;
}

// ---------------- per-variable fused chain v5: counted-vmcnt pipeline, no atomics ------
// M=128, 1024 threads (16 waves), 4 vars/block, grid (4,64): one var-group per XCD.
// Output: plain stores to per-var-group partial buffers (reduce4 sums them) --
// removes ~270 MB of device-scope fp32 atomic RMW fabric traffic (R8: WRITE 321 MB).
// x loads are non-temporal so the 268 MB x-stream stops evicting the 2 MB/XCD weights.
__global__ __launch_bounds__(1024, 1) void var_chain(
    const float* __restrict__ x, const u16* __restrict__ varw,
    const float* __restrict__ vba, const float* __restrict__ vbi,
    const float* __restrict__ vbglu, const float* __restrict__ vlng,
    const float* __restrict__ vlnb, const float* __restrict__ sw,
    float* __restrict__ outp)
{
  extern __shared__ u16 smem[];
  u16* const xt1 = smem;                        // 32768 u16 (64KB): x -> av -> iv in place
  u16* const wtb = smem + 32768;                // 2 x 16384 u16 (2 x 32KB) weight dbuf
  float* const red   = (float*)(smem + 65536);  // [128][4][2] floats (4KB)
  float* const muinv = red + 1024;              // [128][2] floats (1KB)

  const int tid = threadIdx.x;
  const int w = tid >> 6, lane = tid & 63;
  const int q = lane >> 4, c = lane & 15;
  const int rt = w >> 2, cg = w & 3;
  const int vbase = blockIdx.x * 4;
  const int n0 = blockIdx.y * 128;

  f32x4 outacc[2][4];
#pragma unroll
  for (int p = 0; p < 2; ++p)
#pragma unroll
    for (int u = 0; u < 4; ++u) outacc[p][u] = f32x4{0.f, 0.f, 0.f, 0.f};

  auto STAGE = [&](int b, int tn) {  // stage 32KB tile tn into wtb[b]; 2 loads/wave
    const u16* tb = varw + (size_t)(vbase + (tn >> 4)) * 262144 + (size_t)(tn & 15) * 16384;
    u16* dst = wtb + (b << 14);
#pragma unroll
    for (int i = 0; i < 2; ++i) {
      const int cb = (i * 16 + w) * 64;
      gl_lds16(tb + (size_t)(cb + lane) * 8, dst + (size_t)cb * 8);
    }
  };
  auto XSTAGE = [&](int v) {  // xt1 = x tile (nontemporal; source columns pre-permuted)
#pragma unroll
    for (int jj = 0; jj < 4; ++jj) {
      const int cid = jj * 1024 + tid;
      const int r = cid >> 5, p = cid & 31;
      const int l = (p & 24) | ((p & 7) ^ (r & 7));
      const f32x4* s = (const f32x4*)(x + (size_t)(n0 + r) * 4096 + (size_t)v * 256 + l * 8);
      f32x4 v0 = __builtin_nontemporal_load(s);
      f32x4 v1 = __builtin_nontemporal_load(s + 1);
      *(u16x8*)&xt1[cid * 8] = cvt8v(v0, v1);
    }
  };

  auto ROUND_TAIL = [&](int t) {
    __builtin_amdgcn_s_barrier();                    // B1: reads of buf done block-wide
    __builtin_amdgcn_sched_barrier(0);
    STAGE(t & 1, (t + 2 < 64) ? t + 2 : 63);
    __builtin_amdgcn_sched_barrier(0);
    asm volatile("s_waitcnt vmcnt(2)" ::: "memory"); // stage(t+1) resident (per-wave)
    __builtin_amdgcn_sched_barrier(0);
    __builtin_amdgcn_s_barrier();                    // B2: block-wide
    __builtin_amdgcn_sched_barrier(0);
  };

  // prologue: tiles 0,1 in flight; x tile for var 0; one full drain
  STAGE(0, 0);
  STAGE(1, 1);
  XSTAGE(vbase);
  __syncthreads();

  int t = 0;  // global tile counter 0..63 (16 per var)
  for (int vi = 0; vi < 4; ++vi) {
    const int v = vbase + vi;

    f32x4 acc2[2][4];
#pragma unroll
    for (int p = 0; p < 2; ++p)
#pragma unroll
      for (int ti = 0; ti < 4; ++ti) acc2[p][ti] = f32x4{0.f, 0.f, 0.f, 0.f};

    // ---- m1: av = elu(x @ WaT + ba), 4 rounds ----
    for (int kc = 0; kc < 4; ++kc, ++t) {
      const u16* wcur = wtb + ((t & 1) << 14);
      __builtin_amdgcn_s_setprio(1);
#pragma unroll
      for (int kk = 0; kk < 2; ++kk) {
        bf16x8 a[2];
#pragma unroll
        for (int p = 0; p < 2; ++p) {
          const int r = (rt * 2 + p) * 16 + c;
          a[p] = *(const bf16x8*)&xt1[(r * 256 + kc * 64 + kk * 32 + q * 8) ^ ((r & 7) << 3)];
        }
#pragma unroll
        for (int ti = 0; ti < 4; ++ti) {
          const int n16 = (cg * 4 + ti) * 16 + c;
          bf16x8 b = *(const bf16x8*)&wcur[(n16 * 64 + kk * 32 + q * 8) ^ ((n16 & 7) << 3)];
          acc2[0][ti] = mfma16(a[0], b, acc2[0][ti]);
          acc2[1][ti] = mfma16(a[1], b, acc2[1][ti]);
        }
      }
      __builtin_amdgcn_s_setprio(0);
      ROUND_TAIL(t);
    }
    // write av into xt1 (full drain keeps the writeback race-free)
#pragma unroll
    for (int p = 0; p < 2; ++p)
#pragma unroll
      for (int ti = 0; ti < 4; ++ti) {
        const int col = (cg * 4 + ti) * 16 + c;
        const float bb = vba[v * 256 + col];
#pragma unroll
        for (int j = 0; j < 4; ++j) {
          const int row = (rt * 2 + p) * 16 + q * 4 + j;
          float vv = acc2[p][ti][j] + bb;
          vv = vv > 0.f ? vv : expm1f(vv);
          xt1[(row * 256 + col) ^ ((row & 7) << 3)] = f2b(vv);
        }
      }
    __syncthreads();

    // ---- m2: iv = av @ WiT + bi, 4 rounds ----
#pragma unroll
    for (int p = 0; p < 2; ++p)
#pragma unroll
      for (int ti = 0; ti < 4; ++ti) acc2[p][ti] = f32x4{0.f, 0.f, 0.f, 0.f};
    for (int kc = 0; kc < 4; ++kc, ++t) {
      const u16* wcur = wtb + ((t & 1) << 14);
      __builtin_amdgcn_s_setprio(1);
#pragma unroll
      for (int kk = 0; kk < 2; ++kk) {
        bf16x8 a[2];
#pragma unroll
        for (int p = 0; p < 2; ++p) {
          const int r = (rt * 2 + p) * 16 + c;
          a[p] = *(const bf16x8*)&xt1[(r * 256 + kc * 64 + kk * 32 + q * 8) ^ ((r & 7) << 3)];
        }
#pragma unroll
        for (int ti = 0; ti < 4; ++ti) {
          const int n16 = (cg * 4 + ti) * 16 + c;
          bf16x8 b = *(const bf16x8*)&wcur[(n16 * 64 + kk * 32 + q * 8) ^ ((n16 & 7) << 3)];
          acc2[0][ti] = mfma16(a[0], b, acc2[0][ti]);
          acc2[1][ti] = mfma16(a[1], b, acc2[1][ti]);
        }
      }
      __builtin_amdgcn_s_setprio(0);
      ROUND_TAIL(t);
    }
    // write iv into xt1
#pragma unroll
    for (int p = 0; p < 2; ++p)
#pragma unroll
      for (int ti = 0; ti < 4; ++ti) {
        const int col = (cg * 4 + ti) * 16 + c;
        const float bb = vbi[v * 256 + col];
#pragma unroll
        for (int j = 0; j < 4; ++j) {
          const int row = (rt * 2 + p) * 16 + q * 4 + j;
          xt1[(row * 256 + col) ^ ((row & 7) << 3)] = f2b(acc2[p][ti][j] + bb);
        }
      }
    __syncthreads();

    // ---- m3: gv = iv @ WgluT (N=512), 8 rounds ----
    f32x4 acc3[2][8];
#pragma unroll
    for (int p = 0; p < 2; ++p)
#pragma unroll
      for (int u = 0; u < 8; ++u) acc3[p][u] = f32x4{0.f, 0.f, 0.f, 0.f};
    for (int kc = 0; kc < 8; ++kc, ++t) {
      const u16* wcur = wtb + ((t & 1) << 14);
      bf16x8 a[2];
#pragma unroll
      for (int p = 0; p < 2; ++p) {
        const int r = (rt * 2 + p) * 16 + c;
        a[p] = *(const bf16x8*)&xt1[(r * 256 + kc * 32 + q * 8) ^ ((r & 7) << 3)];
      }
      __builtin_amdgcn_s_setprio(1);
#pragma unroll
      for (int u = 0; u < 8; ++u) {
        const int ct = cg * 4 + (u & 3) + ((u >> 2) << 4);
        const int n = ct * 16 + c;
        const int idx = (n >> 1) * 64 + ((((n & 1) * 4 + q) ^ ((n >> 1) & 7)) * 8);
        bf16x8 b = *(const bf16x8*)&wcur[idx];
        acc3[0][u] = mfma16(a[0], b, acc3[0][u]);
        acc3[1][u] = mfma16(a[1], b, acc3[1][u]);
      }
      __builtin_amdgcn_s_setprio(0);
      ROUND_TAIL(t);
    }

    // ---- epilogue: GLU + residual (global, nontemporal) + LN + weighted accumulate ----
    float b1v[4], b2v[4], lgv[4], lbv[4];
#pragma unroll
    for (int u = 0; u < 4; ++u) {
      const int col = cg * 64 + u * 16 + c;
      b1v[u] = vbglu[v * 512 + col];
      b2v[u] = vbglu[v * 512 + 256 + col];
      lgv[u] = vlng[v * 256 + col];
      lbv[u] = vlnb[v * 256 + col];
    }
    float rs[2][4], rss[2][4];
#pragma unroll
    for (int p = 0; p < 2; ++p)
#pragma unroll
      for (int j = 0; j < 4; ++j) { rs[p][j] = 0.f; rss[p][j] = 0.f; }
#pragma unroll
    for (int p = 0; p < 2; ++p)
#pragma unroll
      for (int u = 0; u < 4; ++u) {
        const int col = cg * 64 + u * 16 + c;
#pragma unroll
        for (int j = 0; j < 4; ++j) {
          const int row = (rt * 2 + p) * 16 + q * 4 + j;
          const float g1 = acc3[p][u][j] + b1v[u];
          const float g2 = acc3[p][u + 4][j] + b2v[u];
          const float glu = g1 / (1.f + __expf(-g2));
          const float resid = __builtin_nontemporal_load(
              &x[(size_t)(n0 + row) * 4096 + (size_t)v * 256 + col]);
          const float r = glu + resid;
          acc3[p][u][j] = r;
          rs[p][j] += r; rss[p][j] += r * r;
        }
      }
#pragma unroll
    for (int p = 0; p < 2; ++p)
#pragma unroll
      for (int j = 0; j < 4; ++j)
#pragma unroll
        for (int d = 1; d < 16; d <<= 1) {
          rs[p][j]  += __shfl_xor(rs[p][j], d, 64);
          rss[p][j] += __shfl_xor(rss[p][j], d, 64);
        }
    if (c == 0) {
#pragma unroll
      for (int p = 0; p < 2; ++p)
#pragma unroll
        for (int j = 0; j < 4; ++j) {
          const int row = (rt * 2 + p) * 16 + q * 4 + j;
          red[row * 8 + cg * 2]     = rs[p][j];
          red[row * 8 + cg * 2 + 1] = rss[p][j];
        }
    }
    __syncthreads();
    if (tid < 128) {
      float ms = 0.f, vs = 0.f;
#pragma unroll
      for (int ww = 0; ww < 4; ++ww) { ms += red[tid * 8 + ww * 2]; vs += red[tid * 8 + ww * 2 + 1]; }
      const float mm = ms * (1.f / 256.f);
      muinv[tid * 2]     = mm;
      muinv[tid * 2 + 1] = rsqrtf(vs * (1.f / 256.f) - mm * mm + 1e-5f);
    }
    __syncthreads();
#pragma unroll
    for (int p = 0; p < 2; ++p) {
#pragma unroll
      for (int j = 0; j < 4; ++j) {
        const int row = (rt * 2 + p) * 16 + q * 4 + j;
        const float mu = muinv[row * 2], inv = muinv[row * 2 + 1];
        const float wv = sw[(size_t)(n0 + row) * 16 + v];
#pragma unroll
        for (int u = 0; u < 4; ++u) {
          const float tv = (acc3[p][u][j] - mu) * inv * lgv[u] + lbv[u];
          outacc[p][u][j] += tv * wv;
        }
      }
    }
    __syncthreads();  // muinv/red reads done before next var reuses LDS
    if (vi < 3) {
      XSTAGE(v + 1);
      __syncthreads();  // xt1(x) visible; pipeline tiles stay resident
    }
  }

  // plain stores to this var-group's private partial buffer (no atomics)
  float* const dst = outp + (size_t)blockIdx.x * 2097152;
#pragma unroll
  for (int p = 0; p < 2; ++p)
#pragma unroll
    for (int u = 0; u < 4; ++u) {
      const int col = cg * 64 + u * 16 + c;
#pragma unroll
      for (int j = 0; j < 4; ++j) {
        const int row = (rt * 2 + p) * 16 + q * 4 + j;
        dst[(size_t)(n0 + row) * 256 + col] = outacc[p][u][j];
      }
    }
}

extern "C" void kernel_launch(void* const* d_in, const int* in_sizes, int n_in,
                              void* d_out, int out_size, void* d_ws, size_t ws_size,
                              hipStream_t stream) {
  const float* x     = (const float*)d_in[0];
  const float* ctx   = (const float*)d_in[1];
  const float* jWa   = (const float*)d_in[2];
  const float* jba   = (const float*)d_in[3];
  const float* jWc   = (const float*)d_in[4];
  const float* jWi   = (const float*)d_in[5];
  const float* jbi   = (const float*)d_in[6];
  const float* jWglu = (const float*)d_in[7];
  const float* jbglu = (const float*)d_in[8];
  const float* jWskip= (const float*)d_in[9];
  const float* jbskip= (const float*)d_in[10];
  const float* jlng  = (const float*)d_in[11];
  const float* jlnb  = (const float*)d_in[12];
  const float* vWa   = (const float*)d_in[13];
  const float* vba   = (const float*)d_in[14];
  const float* vWi   = (const float*)d_in[15];
  const float* vbi   = (const float*)d_in[16];
  const float* vWglu = (const float*)d_in[17];
  const float* vbglu = (const float*)d_in[18];
  const float* vlng  = (const float*)d_in[19];
  const float* vlnb  = (const float*)d_in[20];
  float* out = (float*)d_out;

  char* ws = (char*)d_ws;
  size_t off = 0;
  auto alloc = [&](size_t bytes) { void* p = ws + off; off += (bytes + 255) & ~(size_t)255; return p; };
  u16* bt1     = (u16*)alloc((size_t)272 * 4352 * 2);
  u16* wiT     = (u16*)alloc((size_t)256 * 256 * 2);
  u16* wgluT   = (u16*)alloc((size_t)32 * 256 * 2);
  u16* varw    = (u16*)alloc((size_t)16 * 262144 * 2);   // 16 vars x 16 tiles x 32KB
  u16* a_bf    = (u16*)alloc((size_t)8192 * 256 * 2);
  u16* i_bf    = (u16*)alloc((size_t)8192 * 256 * 2);
  float* skipf = (float*)alloc((size_t)8192 * 16 * 4);
  float* outp  = (float*)alloc((size_t)4 * 8192 * 256 * 4); // 32 MB partials

  hipMemsetAsync(bt1, 0, (size_t)272 * 4352 * 2, stream);

  dim3 blk(256);
  transpose_cast<<<dim3(8, 128, 1),  blk, 0, stream>>>(jWa,   bt1,              4096, 256, 4352, 0, 0);
  transpose_cast<<<dim3(8, 8, 1),    blk, 0, stream>>>(jWc,   bt1 + 4096,       256,  256, 4352, 0, 0);
  transpose_cast<<<dim3(1, 128, 1),  blk, 0, stream>>>(jWskip,bt1 + 256 * 4352, 4096, 16,  4352, 0, 0);
  transpose_cast<<<dim3(8, 8, 1),    blk, 0, stream>>>(jWi,   wiT,   256, 256, 256, 0, 0);
  transpose_cast<<<dim3(1, 8, 1),    blk, 0, stream>>>(jWglu, wgluT, 256, 32,  256, 0, 0);
  var_w_prep<<<dim3(16, 4), blk, 0, stream>>>(vWa, varw, 0);
  var_w_prep<<<dim3(16, 4), blk, 0, stream>>>(vWi, varw, 4);
  var_wglu_prep<<<dim3(16, 8), blk, 0, stream>>>(vWglu, varw);

  gemm1<<<dim3(256), blk, 0, stream>>>(x, ctx, bt1, jba, jbskip, a_bf, skipf);
  gemm_i<<<dim3(256), blk, 0, stream>>>(a_bf, wiT, jbi, i_bf);
  joint_tail<<<dim3(2048), blk, 0, stream>>>(i_bf, wgluT, jbglu, skipf, jlng, jlnb,
                                             out + (size_t)8192 * 256);

  hipFuncSetAttribute((const void*)var_chain, hipFuncAttributeMaxDynamicSharedMemorySize, 136192);
  var_chain<<<dim3(4, 64), dim3(1024), 136192, stream>>>(x, varw, vba, vbi, vbglu,
                                                         vlng, vlnb,
                                                         out + (size_t)8192 * 256, outp);
  reduce4<<<dim3(2048), blk, 0, stream>>>(outp, out);
}